// Round 5
// baseline (1685.929 us; speedup 1.0000x reference)
//
#include <hip/hip_runtime.h>

#define NN 50000
#define NE 1600000
#define NG 512
#define IN_DIM 128
#define HID 64

#define NB 128                       // nodes per bucket
#define NBK ((NN + NB - 1) / NB)     // 391 buckets
#define EBLK 512                     // edge-pass blocks
#define EPB (NE / EBLK)              // 3125 edges per block

// ---- pass 1: per-block coarse histogram of dst>>7 ----
__global__ void cnt_kernel(const int* __restrict__ ei, int* __restrict__ pcnt) {
    __shared__ int h[NBK];
    for (int i = threadIdx.x; i < NBK; i += blockDim.x) h[i] = 0;
    __syncthreads();
    int base = blockIdx.x * EPB;
    for (int e = base + threadIdx.x; e < base + EPB; e += blockDim.x)
        atomicAdd(&h[ei[NE + e] >> 7], 1);
    __syncthreads();
    for (int i = threadIdx.x; i < NBK; i += blockDim.x)
        pcnt[(size_t)i * EBLK + blockIdx.x] = h[i];
}

// ---- pass 2a: per-bucket exclusive scan over the EBLK partials ----
__global__ void bscan_kernel(int* __restrict__ pcnt, int* __restrict__ tot) {
    __shared__ int s[EBLK];
    int k = blockIdx.x, t = threadIdx.x;
    int v = pcnt[(size_t)k * EBLK + t];
    s[t] = v;
    __syncthreads();
    for (int off = 1; off < EBLK; off <<= 1) {
        int add = (t >= off) ? s[t - off] : 0;
        __syncthreads();
        s[t] += add;
        __syncthreads();
    }
    pcnt[(size_t)k * EBLK + t] = s[t] - v;   // exclusive within bucket
    if (t == EBLK - 1) tot[k] = s[t];
}

// ---- pass 2b: exclusive scan of bucket totals -> bbase[0..NBK] ----
__global__ void tscan_kernel(const int* __restrict__ tot, int* __restrict__ bbase) {
    __shared__ int s[512];
    int t = threadIdx.x;
    int v = (t < NBK) ? tot[t] : 0;
    s[t] = v;
    __syncthreads();
    for (int off = 1; off < 512; off <<= 1) {
        int add = (t >= off) ? s[t - off] : 0;
        __syncthreads();
        s[t] += add;
        __syncthreads();
    }
    if (t < NBK) bbase[t] = s[t] - v;
    if (t == NBK - 1) bbase[NBK] = s[t];
}

// ---- pass 3: scatter records {dl:7|src:17, ea} grouped by bucket ----
__global__ void scatter_kernel(const int* __restrict__ ei, const float* __restrict__ ea,
                               const int* __restrict__ pcnt, const int* __restrict__ bbase,
                               int2* __restrict__ recs) {
    __shared__ int curs[NBK];
    int b = blockIdx.x;
    for (int i = threadIdx.x; i < NBK; i += blockDim.x)
        curs[i] = bbase[i] + pcnt[(size_t)i * EBLK + b];
    __syncthreads();
    int base = b * EPB;
    for (int e = base + threadIdx.x; e < base + EPB; e += blockDim.x) {
        int dst = ei[NE + e];
        int src = ei[e];
        int k = dst >> 7;
        int pos = atomicAdd(&curs[k], 1);
        recs[pos] = make_int2(((dst & 127) << 17) | src, __float_as_int(ea[e]));
    }
}

// ---- weighted in-degree per bucket -> dis = rsqrt(1+deg) ----
__global__ void bdeg_kernel(const int2* __restrict__ recs, const int* __restrict__ bbase,
                            float* __restrict__ dis) {
    __shared__ float deg[NB];
    int k = blockIdx.x;
    int lo = k * NB;
    int nLoc = min(NB, NN - lo);
    for (int i = threadIdx.x; i < nLoc; i += blockDim.x) deg[i] = 0.f;
    __syncthreads();
    int start = bbase[k], end = bbase[k + 1];
    for (int e = start + threadIdx.x; e < end; e += blockDim.x) {
        int2 r = recs[e];
        atomicAdd(&deg[r.x >> 17], __int_as_float(r.y));
    }
    __syncthreads();
    for (int i = threadIdx.x; i < nLoc; i += blockDim.x)
        dis[lo + i] = rsqrtf(deg[i] + 1.0f);
}

// Y[n,HID] = X[n,K] @ W[K,HID].  W staged in LDS. 1 wave per row, lane = col.
template <int K>
__global__ void gemm_kernel(const float* __restrict__ X,
                            const float* __restrict__ W,
                            float* __restrict__ Y) {
    __shared__ float w_lds[K * HID];
    for (int idx = threadIdx.x; idx < K * HID; idx += blockDim.x)
        w_lds[idx] = W[idx];
    __syncthreads();
    int wave = threadIdx.x >> 6;
    int lane = threadIdx.x & 63;
    int row = blockIdx.x * 4 + wave;
    if (row >= NN) return;
    const float4* x4 = (const float4*)(X + (size_t)row * K);
    float acc = 0.0f;
#pragma unroll
    for (int k4 = 0; k4 < K / 4; ++k4) {
        float4 xv = x4[k4];
        acc += xv.x * w_lds[(k4 * 4 + 0) * HID + lane];
        acc += xv.y * w_lds[(k4 * 4 + 1) * HID + lane];
        acc += xv.z * w_lds[(k4 * 4 + 2) * HID + lane];
        acc += xv.w * w_lds[(k4 * 4 + 3) * HID + lane];
    }
    Y[(size_t)row * HID + lane] = acc;
}

// ---- bucket aggregation: acc[128][64] in LDS, edges broadcast via shfl ----
template <bool RELU>
__global__ void agg_kernel(const int2* __restrict__ recs, const int* __restrict__ bbase,
                           const float* __restrict__ dis, const float* __restrict__ HW,
                           const float* __restrict__ bias, float* __restrict__ OUT) {
    __shared__ float acc[NB * HID];   // 32 KB
    __shared__ float wdst[NB];
    int k = blockIdx.x;
    int lo = k * NB;
    int nLoc = min(NB, NN - lo);
    int tid = threadIdx.x;
    for (int i = tid; i < nLoc; i += blockDim.x) wdst[i] = dis[lo + i];
    __syncthreads();
    // self-loop init: acc[nl][c] = dis^2 * HW[lo+nl][c]
    for (int i = tid; i < nLoc * HID; i += blockDim.x) {
        float d = wdst[i >> 6];
        acc[i] = d * d * HW[(size_t)lo * HID + i];
    }
    __syncthreads();
    int start = bbase[k], end = bbase[k + 1];
    int lane = tid & 63;
    int wv = tid >> 6;
    int nw = blockDim.x >> 6;
    for (int ebase = start + wv * 64; ebase < end; ebase += nw * 64) {
        int myidx = ebase + lane;
        int pk = 0;
        float wl = 0.f;
        if (myidx < end) {
            int2 r = recs[myidx];
            pk = r.x;
            int src = r.x & 0x1FFFF;
            int dl = r.x >> 17;
            wl = dis[src] * __int_as_float(r.y) * wdst[dl];
        }
        int cnt = min(64, end - ebase);
#pragma unroll 4
        for (int j = 0; j < cnt; ++j) {
            int pj = __shfl(pk, j, 64);
            float wj = __shfl(wl, j, 64);
            int src = pj & 0x1FFFF;
            int dl = pj >> 17;
            atomicAdd(&acc[(dl << 6) | lane], wj * HW[(size_t)src * HID + lane]);
        }
    }
    __syncthreads();
    for (int i = tid; i < nLoc * HID; i += blockDim.x) {
        float v = acc[i] + bias[i & 63];
        OUT[(size_t)lo * HID + i] = RELU ? fmaxf(v, 0.0f) : v;
    }
}

// gstart[g] = lower_bound(batch, g)   (batch sorted); gstart[NG] = NN
__global__ void gbounds_kernel(const int* __restrict__ batch, int* __restrict__ gstart) {
    int g = blockIdx.x * blockDim.x + threadIdx.x;
    if (g > NG) return;
    int lo = 0, hi = NN;
    while (lo < hi) {
        int mid = (lo + hi) >> 1;
        if (batch[mid] < g) lo = mid + 1; else hi = mid;
    }
    gstart[g] = lo;
}

// out[g] = (mean of H rows in [gstart[g],gstart[g+1])) . Wlin + blin
__global__ void pool_head_kernel(const float* __restrict__ H,
                                 const int* __restrict__ gstart,
                                 const float* __restrict__ Wlin,
                                 const float* __restrict__ blin,
                                 float* __restrict__ out) {
    int g = blockIdx.x;
    int lane = threadIdx.x;
    int s = gstart[g], e = gstart[g + 1];
    float a0 = 0.f, a1 = 0.f, a2 = 0.f, a3 = 0.f;
    int i = s;
    for (; i + 4 <= e; i += 4) {
        a0 += H[(size_t)(i + 0) * HID + lane];
        a1 += H[(size_t)(i + 1) * HID + lane];
        a2 += H[(size_t)(i + 2) * HID + lane];
        a3 += H[(size_t)(i + 3) * HID + lane];
    }
    for (; i < e; ++i) a0 += H[(size_t)i * HID + lane];
    float mean = ((a0 + a1) + (a2 + a3)) / fmaxf((float)(e - s), 1.0f);
    float v = mean * Wlin[lane];
    for (int off = 32; off > 0; off >>= 1) v += __shfl_down(v, off, 64);
    if (lane == 0) out[g] = v + blin[0];
}

extern "C" void kernel_launch(void* const* d_in, const int* in_sizes, int n_in,
                              void* d_out, int out_size, void* d_ws, size_t ws_size,
                              hipStream_t stream) {
    const float* x     = (const float*)d_in[0];
    const int*   ei    = (const int*)d_in[1];
    const float* ea    = (const float*)d_in[2];
    const int*   batch = (const int*)d_in[3];
    const float* W1    = (const float*)d_in[4];
    const float* b1    = (const float*)d_in[5];
    const float* W2    = (const float*)d_in[6];
    const float* b2    = (const float*)d_in[7];
    const float* Wlin  = (const float*)d_in[8];
    const float* blin  = (const float*)d_in[9];
    float*       out   = (float*)d_out;

    char* ws = (char*)d_ws;
    auto alloc = [&](size_t bytes) {
        void* p = (void*)ws;
        ws += (bytes + 255) / 256 * 256;
        return p;
    };
    float* dis    = (float*)alloc((size_t)NN * 4);
    int*   pcnt   = (int*)alloc((size_t)NBK * EBLK * 4);
    int*   tot    = (int*)alloc((size_t)NBK * 4);
    int*   bbase  = (int*)alloc((size_t)(NBK + 1) * 4);
    int*   gstart = (int*)alloc((size_t)(NG + 1) * 4);
    int2*  recs   = (int2*)alloc((size_t)NE * 8);
    float* A      = (float*)alloc((size_t)NN * HID * 4);   // hw1 then hw2
    float* B      = (float*)alloc((size_t)NN * HID * 4);   // h1 then h2

    // bucket sort of edges by dst>>7 (no global atomics)
    cnt_kernel<<<EBLK, 256, 0, stream>>>(ei, pcnt);
    bscan_kernel<<<NBK, EBLK, 0, stream>>>(pcnt, tot);
    tscan_kernel<<<1, 512, 0, stream>>>(tot, bbase);
    scatter_kernel<<<EBLK, 256, 0, stream>>>(ei, ea, pcnt, bbase, recs);
    bdeg_kernel<<<NBK, 256, 0, stream>>>(recs, bbase, dis);

    // conv1: h1 = relu(agg(x@W1) + self + b1)
    gemm_kernel<IN_DIM><<<(NN + 3) / 4, 256, 0, stream>>>(x, W1, A);
    agg_kernel<true><<<NBK, 512, 0, stream>>>(recs, bbase, dis, A, b1, B);

    // conv2: h2 = agg(h1@W2) + self + b2
    gemm_kernel<HID><<<(NN + 3) / 4, 256, 0, stream>>>(B, W2, A);
    agg_kernel<false><<<NBK, 512, 0, stream>>>(recs, bbase, dis, A, b2, B);

    // mean-pool per sorted-contiguous graph range + head
    gbounds_kernel<<<(NG + 256) / 256, 256, 0, stream>>>(batch, gstart);
    pool_head_kernel<<<NG, 64, 0, stream>>>(B, gstart, Wlin, blin, out);
}

// Round 6
// 342.479 us; speedup vs baseline: 4.9227x; 4.9227x over previous
//
#include <hip/hip_runtime.h>

#define NN 50000
#define NE 1600000
#define NG 512
#define IN_DIM 128
#define HID 64

#define NB 128                       // nodes per bucket
#define NBK ((NN + NB - 1) / NB)     // 391 buckets
#define EBLK 512                     // edge-pass blocks
#define EPB (NE / EBLK)              // 3125 edges per block
#define CHUNK 512
#define NCH ((NN + CHUNK - 1) / CHUNK)   // 98

// ---- pass 1: per-block coarse histogram of dst>>7 ----
__global__ void cnt_kernel(const int* __restrict__ ei, int* __restrict__ pcnt) {
    __shared__ int h[NBK];
    for (int i = threadIdx.x; i < NBK; i += blockDim.x) h[i] = 0;
    __syncthreads();
    int base = blockIdx.x * EPB;
    for (int e = base + threadIdx.x; e < base + EPB; e += blockDim.x)
        atomicAdd(&h[ei[NE + e] >> 7], 1);
    __syncthreads();
    for (int i = threadIdx.x; i < NBK; i += blockDim.x)
        pcnt[(size_t)i * EBLK + blockIdx.x] = h[i];
}

// ---- pass 2a: per-bucket exclusive scan over the EBLK partials ----
__global__ void bscan_kernel(int* __restrict__ pcnt, int* __restrict__ tot) {
    __shared__ int s[EBLK];
    int k = blockIdx.x, t = threadIdx.x;
    int v = pcnt[(size_t)k * EBLK + t];
    s[t] = v;
    __syncthreads();
    for (int off = 1; off < EBLK; off <<= 1) {
        int add = (t >= off) ? s[t - off] : 0;
        __syncthreads();
        s[t] += add;
        __syncthreads();
    }
    pcnt[(size_t)k * EBLK + t] = s[t] - v;   // exclusive within bucket
    if (t == EBLK - 1) tot[k] = s[t];
}

// ---- pass 2b: exclusive scan of bucket totals -> bbase[0..NBK] ----
__global__ void tscan_kernel(const int* __restrict__ tot, int* __restrict__ bbase) {
    __shared__ int s[512];
    int t = threadIdx.x;
    int v = (t < NBK) ? tot[t] : 0;
    s[t] = v;
    __syncthreads();
    for (int off = 1; off < 512; off <<= 1) {
        int add = (t >= off) ? s[t - off] : 0;
        __syncthreads();
        s[t] += add;
        __syncthreads();
    }
    if (t < NBK) bbase[t] = s[t] - v;
    if (t == NBK - 1) bbase[NBK] = s[t];
}

// ---- pass 3: scatter records {dl:7|src:17, ea} grouped by bucket ----
__global__ void scatter_kernel(const int* __restrict__ ei, const float* __restrict__ ea,
                               const int* __restrict__ pcnt, const int* __restrict__ bbase,
                               int2* __restrict__ recs) {
    __shared__ int curs[NBK];
    int b = blockIdx.x;
    for (int i = threadIdx.x; i < NBK; i += blockDim.x)
        curs[i] = bbase[i] + pcnt[(size_t)i * EBLK + b];
    __syncthreads();
    int base = b * EPB;
    for (int e = base + threadIdx.x; e < base + EPB; e += blockDim.x) {
        int dst = ei[NE + e];
        int src = ei[e];
        int k = dst >> 7;
        int pos = atomicAdd(&curs[k], 1);
        recs[pos] = make_int2(((dst & 127) << 17) | src, __float_as_int(ea[e]));
    }
}

// ---- per-bucket: indeg[node], dis[node] = rsqrt(1 + weighted deg) ----
__global__ void binfo_kernel(const int2* __restrict__ recs, const int* __restrict__ bbase,
                             int* __restrict__ indeg, float* __restrict__ dis) {
    __shared__ float deg[NB];
    __shared__ int cnt[NB];
    int k = blockIdx.x;
    int lo = k * NB;
    int nLoc = min(NB, NN - lo);
    for (int i = threadIdx.x; i < nLoc; i += blockDim.x) { deg[i] = 0.f; cnt[i] = 0; }
    __syncthreads();
    int start = bbase[k], end = bbase[k + 1];
    for (int e = start + threadIdx.x; e < end; e += blockDim.x) {
        int2 r = recs[e];
        int dl = r.x >> 17;
        atomicAdd(&deg[dl], __int_as_float(r.y));
        atomicAdd(&cnt[dl], 1);
    }
    __syncthreads();
    for (int i = threadIdx.x; i < nLoc; i += blockDim.x) {
        indeg[lo + i] = cnt[i];
        dis[lo + i] = rsqrtf(deg[i] + 1.0f);
    }
}

// ---- 3-phase exclusive scan of indeg -> offs ----
__global__ void chunksum_kernel(const int* __restrict__ cnt, int* __restrict__ csum) {
    __shared__ int s[256];
    int b = blockIdx.x, t = threadIdx.x;
    int base = b * CHUNK;
    int v = 0;
    for (int i = t; i < CHUNK; i += 256) {
        int idx = base + i;
        if (idx < NN) v += cnt[idx];
    }
    s[t] = v;
    __syncthreads();
    for (int off = 128; off > 0; off >>= 1) {
        if (t < off) s[t] += s[t + off];
        __syncthreads();
    }
    if (t == 0) csum[b] = s[0];
}

__global__ void scanchunks_kernel(const int* __restrict__ csum, int* __restrict__ coff) {
    __shared__ int s[128];
    int t = threadIdx.x;
    int v = (t < NCH) ? csum[t] : 0;
    s[t] = v;
    __syncthreads();
    for (int off = 1; off < 128; off <<= 1) {
        int add = (t >= off) ? s[t - off] : 0;
        __syncthreads();
        s[t] += add;
        __syncthreads();
    }
    if (t < NCH) coff[t] = s[t] - v;   // exclusive
}

__global__ void chunkscan_kernel(const int* __restrict__ cnt,
                                 const int* __restrict__ coff,
                                 int* __restrict__ offs) {
    __shared__ int s[CHUNK];
    int b = blockIdx.x, t = threadIdx.x;
    int idx = b * CHUNK + t;
    int v = (idx < NN) ? cnt[idx] : 0;
    s[t] = v;
    __syncthreads();
    for (int off = 1; off < CHUNK; off <<= 1) {
        int add = (t >= off) ? s[t - off] : 0;
        __syncthreads();
        s[t] += add;
        __syncthreads();
    }
    if (idx < NN) offs[idx] = coff[b] + s[t] - v;
}

// ---- level-2 sort: bucket records -> exact per-node CSR {src, norm} ----
__global__ void sort2_kernel(const int2* __restrict__ recs, const int* __restrict__ bbase,
                             const float* __restrict__ dis, const int* __restrict__ offs,
                             int2* __restrict__ csr) {
    __shared__ int curs[NB];
    __shared__ float wdst[NB];
    int k = blockIdx.x;
    int lo = k * NB;
    int nLoc = min(NB, NN - lo);
    for (int i = threadIdx.x; i < nLoc; i += blockDim.x) {
        curs[i] = offs[lo + i];
        wdst[i] = dis[lo + i];
    }
    __syncthreads();
    int start = bbase[k], end = bbase[k + 1];
    for (int e = start + threadIdx.x; e < end; e += blockDim.x) {
        int2 r = recs[e];
        int src = r.x & 0x1FFFF;
        int dl = r.x >> 17;
        float w = dis[src] * __int_as_float(r.y) * wdst[dl];
        int pos = atomicAdd(&curs[dl], 1);
        csr[pos] = make_int2(src, __float_as_int(w));
    }
}

// Y[n,HID] = X[n,K] @ W[K,HID].  W staged in LDS. 1 wave per row, lane = col.
template <int K>
__global__ void gemm_kernel(const float* __restrict__ X,
                            const float* __restrict__ W,
                            float* __restrict__ Y) {
    __shared__ float w_lds[K * HID];
    for (int idx = threadIdx.x; idx < K * HID; idx += blockDim.x)
        w_lds[idx] = W[idx];
    __syncthreads();
    int wave = threadIdx.x >> 6;
    int lane = threadIdx.x & 63;
    int row = blockIdx.x * 4 + wave;
    if (row >= NN) return;
    const float4* x4 = (const float4*)(X + (size_t)row * K);
    float acc = 0.0f;
#pragma unroll
    for (int k4 = 0; k4 < K / 4; ++k4) {
        float4 xv = x4[k4];
        acc += xv.x * w_lds[(k4 * 4 + 0) * HID + lane];
        acc += xv.y * w_lds[(k4 * 4 + 1) * HID + lane];
        acc += xv.z * w_lds[(k4 * 4 + 2) * HID + lane];
        acc += xv.w * w_lds[(k4 * 4 + 3) * HID + lane];
    }
    Y[(size_t)row * HID + lane] = acc;
}

// OUT[node] = act( sum_e w*HW[src] + dis^2*HW[node] + bias )   (1 wave/node)
template <bool RELU>
__global__ void gather_kernel(const int2* __restrict__ csr,
                              const int* __restrict__ offs,
                              const int* __restrict__ indeg,
                              const float* __restrict__ dis,
                              const float* __restrict__ HW,
                              const float* __restrict__ bias,
                              float* __restrict__ OUT) {
    int node = blockIdx.x * 4 + (threadIdx.x >> 6);
    int lane = threadIdx.x & 63;
    if (node >= NN) return;
    int start = offs[node];
    int n = indeg[node];
    float d = dis[node];
    float a0 = d * d * HW[(size_t)node * HID + lane];
    float a1 = 0.f, a2 = 0.f, a3 = 0.f;
    int j = 0;
    for (; j + 4 <= n; j += 4) {
        int2 r0 = csr[start + j + 0];
        int2 r1 = csr[start + j + 1];
        int2 r2 = csr[start + j + 2];
        int2 r3 = csr[start + j + 3];
        a0 += __int_as_float(r0.y) * HW[(size_t)r0.x * HID + lane];
        a1 += __int_as_float(r1.y) * HW[(size_t)r1.x * HID + lane];
        a2 += __int_as_float(r2.y) * HW[(size_t)r2.x * HID + lane];
        a3 += __int_as_float(r3.y) * HW[(size_t)r3.x * HID + lane];
    }
    for (; j < n; ++j) {
        int2 r = csr[start + j];
        a0 += __int_as_float(r.y) * HW[(size_t)r.x * HID + lane];
    }
    float v = (a0 + a1) + (a2 + a3) + bias[lane];
    OUT[(size_t)node * HID + lane] = RELU ? fmaxf(v, 0.0f) : v;
}

// gstart[g] = lower_bound(batch, g)   (batch sorted); gstart[NG] = NN
__global__ void gbounds_kernel(const int* __restrict__ batch, int* __restrict__ gstart) {
    int g = blockIdx.x * blockDim.x + threadIdx.x;
    if (g > NG) return;
    int lo = 0, hi = NN;
    while (lo < hi) {
        int mid = (lo + hi) >> 1;
        if (batch[mid] < g) lo = mid + 1; else hi = mid;
    }
    gstart[g] = lo;
}

// out[g] = (mean of H rows in [gstart[g],gstart[g+1])) . Wlin + blin  (4 waves/graph)
__global__ void pool_head_kernel(const float* __restrict__ H,
                                 const int* __restrict__ gstart,
                                 const float* __restrict__ Wlin,
                                 const float* __restrict__ blin,
                                 float* __restrict__ out) {
    __shared__ float part[4];
    int g = blockIdx.x;
    int lane = threadIdx.x & 63;
    int wv = threadIdx.x >> 6;
    int s = gstart[g], e = gstart[g + 1];
    float wl = Wlin[lane];
    float a = 0.f;
    for (int i = s + wv; i < e; i += 4) a += H[(size_t)i * HID + lane];
    float v = a * wl;
    for (int off = 32; off > 0; off >>= 1) v += __shfl_down(v, off, 64);
    if (lane == 0) part[wv] = v;
    __syncthreads();
    if (threadIdx.x == 0) {
        float t = part[0] + part[1] + part[2] + part[3];
        out[g] = t / fmaxf((float)(e - s), 1.0f) + blin[0];
    }
}

extern "C" void kernel_launch(void* const* d_in, const int* in_sizes, int n_in,
                              void* d_out, int out_size, void* d_ws, size_t ws_size,
                              hipStream_t stream) {
    const float* x     = (const float*)d_in[0];
    const int*   ei    = (const int*)d_in[1];
    const float* ea    = (const float*)d_in[2];
    const int*   batch = (const int*)d_in[3];
    const float* W1    = (const float*)d_in[4];
    const float* b1    = (const float*)d_in[5];
    const float* W2    = (const float*)d_in[6];
    const float* b2    = (const float*)d_in[7];
    const float* Wlin  = (const float*)d_in[8];
    const float* blin  = (const float*)d_in[9];
    float*       out   = (float*)d_out;

    char* ws = (char*)d_ws;
    auto alloc = [&](size_t bytes) {
        void* p = (void*)ws;
        ws += (bytes + 255) / 256 * 256;
        return p;
    };
    float* dis    = (float*)alloc((size_t)NN * 4);
    int*   indeg  = (int*)alloc((size_t)NN * 4);
    int*   offs   = (int*)alloc((size_t)NN * 4);
    int*   csum   = (int*)alloc((size_t)NCH * 4);
    int*   coff   = (int*)alloc((size_t)NCH * 4);
    int*   pcnt   = (int*)alloc((size_t)NBK * EBLK * 4);
    int*   tot    = (int*)alloc((size_t)NBK * 4);
    int*   bbase  = (int*)alloc((size_t)(NBK + 1) * 4);
    int*   gstart = (int*)alloc((size_t)(NG + 1) * 4);
    int2*  recs   = (int2*)alloc((size_t)NE * 8);   // bucket-grouped; dead after sort2
    int2*  csr    = (int2*)alloc((size_t)NE * 8);   // node-grouped
    float* B      = (float*)alloc((size_t)NN * HID * 4);
    float* A      = (float*)recs;                   // hw1/hw2 alias recs (dead by gemm1)

    // two-level bucket sort of edges by dst (no global atomics)
    cnt_kernel<<<EBLK, 256, 0, stream>>>(ei, pcnt);
    bscan_kernel<<<NBK, EBLK, 0, stream>>>(pcnt, tot);
    tscan_kernel<<<1, 512, 0, stream>>>(tot, bbase);
    scatter_kernel<<<EBLK, 256, 0, stream>>>(ei, ea, pcnt, bbase, recs);
    binfo_kernel<<<NBK, 256, 0, stream>>>(recs, bbase, indeg, dis);
    chunksum_kernel<<<NCH, 256, 0, stream>>>(indeg, csum);
    scanchunks_kernel<<<1, 128, 0, stream>>>(csum, coff);
    chunkscan_kernel<<<NCH, CHUNK, 0, stream>>>(indeg, coff, offs);
    sort2_kernel<<<NBK, 256, 0, stream>>>(recs, bbase, dis, offs, csr);

    // conv1: h1 = relu(gather(x@W1) + self + b1)     (gemm1 overwrites recs)
    gemm_kernel<IN_DIM><<<(NN + 3) / 4, 256, 0, stream>>>(x, W1, A);
    gather_kernel<true><<<(NN + 3) / 4, 256, 0, stream>>>(csr, offs, indeg, dis, A, b1, B);

    // conv2: h2 = gather(h1@W2) + self + b2
    gemm_kernel<HID><<<(NN + 3) / 4, 256, 0, stream>>>(B, W2, A);
    gather_kernel<false><<<(NN + 3) / 4, 256, 0, stream>>>(csr, offs, indeg, dis, A, b2, B);

    // mean-pool per sorted-contiguous graph range + head
    gbounds_kernel<<<(NG + 256) / 256, 256, 0, stream>>>(batch, gstart);
    pool_head_kernel<<<NG, 256, 0, stream>>>(B, gstart, Wlin, blin, out);
}

// Round 7
// 304.870 us; speedup vs baseline: 5.5300x; 1.1234x over previous
//
#include <hip/hip_runtime.h>

#define NN 50000
#define NE 1600000
#define NG 512
#define IN_DIM 128
#define HID 64

#define NB 128                       // nodes per bucket
#define NBK ((NN + NB - 1) / NB)     // 391 buckets
#define EBLK 512                     // edge-pass blocks
#define EPB (NE / EBLK)              // 3125 edges per block
#define CHUNK 512
#define NCH ((NN + CHUNK - 1) / CHUNK)   // 98

// ---- pass 1: per-block coarse histogram of dst>>7 ----
__global__ void cnt_kernel(const int* __restrict__ ei, int* __restrict__ pcnt) {
    __shared__ int h[NBK];
    for (int i = threadIdx.x; i < NBK; i += blockDim.x) h[i] = 0;
    __syncthreads();
    int base = blockIdx.x * EPB;
    for (int e = base + threadIdx.x; e < base + EPB; e += blockDim.x)
        atomicAdd(&h[ei[NE + e] >> 7], 1);
    __syncthreads();
    for (int i = threadIdx.x; i < NBK; i += blockDim.x)
        pcnt[(size_t)i * EBLK + blockIdx.x] = h[i];
}

// ---- pass 2a: per-bucket exclusive scan over the EBLK partials ----
__global__ void bscan_kernel(int* __restrict__ pcnt, int* __restrict__ tot) {
    __shared__ int s[EBLK];
    int k = blockIdx.x, t = threadIdx.x;
    int v = pcnt[(size_t)k * EBLK + t];
    s[t] = v;
    __syncthreads();
    for (int off = 1; off < EBLK; off <<= 1) {
        int add = (t >= off) ? s[t - off] : 0;
        __syncthreads();
        s[t] += add;
        __syncthreads();
    }
    pcnt[(size_t)k * EBLK + t] = s[t] - v;   // exclusive within bucket
    if (t == EBLK - 1) tot[k] = s[t];
}

// ---- pass 2b: exclusive scan of bucket totals -> bbase[0..NBK] ----
__global__ void tscan_kernel(const int* __restrict__ tot, int* __restrict__ bbase) {
    __shared__ int s[512];
    int t = threadIdx.x;
    int v = (t < NBK) ? tot[t] : 0;
    s[t] = v;
    __syncthreads();
    for (int off = 1; off < 512; off <<= 1) {
        int add = (t >= off) ? s[t - off] : 0;
        __syncthreads();
        s[t] += add;
        __syncthreads();
    }
    if (t < NBK) bbase[t] = s[t] - v;
    if (t == NBK - 1) bbase[NBK] = s[t];
}

// ---- pass 3: scatter records {dl:7|src:17, ea} grouped by bucket ----
__global__ void scatter_kernel(const int* __restrict__ ei, const float* __restrict__ ea,
                               const int* __restrict__ pcnt, const int* __restrict__ bbase,
                               int2* __restrict__ recs) {
    __shared__ int curs[NBK];
    int b = blockIdx.x;
    for (int i = threadIdx.x; i < NBK; i += blockDim.x)
        curs[i] = bbase[i] + pcnt[(size_t)i * EBLK + b];
    __syncthreads();
    int base = b * EPB;
    for (int e = base + threadIdx.x; e < base + EPB; e += blockDim.x) {
        int dst = ei[NE + e];
        int src = ei[e];
        int k = dst >> 7;
        int pos = atomicAdd(&curs[k], 1);
        recs[pos] = make_int2(((dst & 127) << 17) | src, __float_as_int(ea[e]));
    }
}

// ---- per-bucket: indeg[node], dis[node] = rsqrt(1 + weighted deg) ----
__global__ void binfo_kernel(const int2* __restrict__ recs, const int* __restrict__ bbase,
                             int* __restrict__ indeg, float* __restrict__ dis) {
    __shared__ float deg[NB];
    __shared__ int cnt[NB];
    int k = blockIdx.x;
    int lo = k * NB;
    int nLoc = min(NB, NN - lo);
    for (int i = threadIdx.x; i < nLoc; i += blockDim.x) { deg[i] = 0.f; cnt[i] = 0; }
    __syncthreads();
    int start = bbase[k], end = bbase[k + 1];
    for (int e = start + threadIdx.x; e < end; e += blockDim.x) {
        int2 r = recs[e];
        int dl = r.x >> 17;
        atomicAdd(&deg[dl], __int_as_float(r.y));
        atomicAdd(&cnt[dl], 1);
    }
    __syncthreads();
    for (int i = threadIdx.x; i < nLoc; i += blockDim.x) {
        indeg[lo + i] = cnt[i];
        dis[lo + i] = rsqrtf(deg[i] + 1.0f);
    }
}

// ---- 3-phase exclusive scan of indeg -> offs ----
__global__ void chunksum_kernel(const int* __restrict__ cnt, int* __restrict__ csum) {
    __shared__ int s[256];
    int b = blockIdx.x, t = threadIdx.x;
    int base = b * CHUNK;
    int v = 0;
    for (int i = t; i < CHUNK; i += 256) {
        int idx = base + i;
        if (idx < NN) v += cnt[idx];
    }
    s[t] = v;
    __syncthreads();
    for (int off = 128; off > 0; off >>= 1) {
        if (t < off) s[t] += s[t + off];
        __syncthreads();
    }
    if (t == 0) csum[b] = s[0];
}

__global__ void scanchunks_kernel(const int* __restrict__ csum, int* __restrict__ coff) {
    __shared__ int s[128];
    int t = threadIdx.x;
    int v = (t < NCH) ? csum[t] : 0;
    s[t] = v;
    __syncthreads();
    for (int off = 1; off < 128; off <<= 1) {
        int add = (t >= off) ? s[t - off] : 0;
        __syncthreads();
        s[t] += add;
        __syncthreads();
    }
    if (t < NCH) coff[t] = s[t] - v;   // exclusive
}

__global__ void chunkscan_kernel(const int* __restrict__ cnt,
                                 const int* __restrict__ coff,
                                 int* __restrict__ offs) {
    __shared__ int s[CHUNK];
    int b = blockIdx.x, t = threadIdx.x;
    int idx = b * CHUNK + t;
    int v = (idx < NN) ? cnt[idx] : 0;
    s[t] = v;
    __syncthreads();
    for (int off = 1; off < CHUNK; off <<= 1) {
        int add = (t >= off) ? s[t - off] : 0;
        __syncthreads();
        s[t] += add;
        __syncthreads();
    }
    if (idx < NN) offs[idx] = coff[b] + s[t] - v;
}

// ---- level-2 sort: bucket records -> exact per-node CSR {src, norm} ----
__global__ void sort2_kernel(const int2* __restrict__ recs, const int* __restrict__ bbase,
                             const float* __restrict__ dis, const int* __restrict__ offs,
                             int2* __restrict__ csr) {
    __shared__ int curs[NB];
    __shared__ float wdst[NB];
    int k = blockIdx.x;
    int lo = k * NB;
    int nLoc = min(NB, NN - lo);
    for (int i = threadIdx.x; i < nLoc; i += blockDim.x) {
        curs[i] = offs[lo + i];
        wdst[i] = dis[lo + i];
    }
    __syncthreads();
    int start = bbase[k], end = bbase[k + 1];
    for (int e = start + threadIdx.x; e < end; e += blockDim.x) {
        int2 r = recs[e];
        int src = r.x & 0x1FFFF;
        int dl = r.x >> 17;
        float w = dis[src] * __int_as_float(r.y) * wdst[dl];
        int pos = atomicAdd(&curs[dl], 1);
        csr[pos] = make_int2(src, __float_as_int(w));
    }
}

// Y[n,HID] = X[n,K] @ W[K,HID].  W in LDS; each wave computes 4 rows x 64 cols
// so every LDS read is amortized over 4 FMAs. 16 rows/block, 3125 blocks exact.
template <int K>
__global__ void gemm_kernel(const float* __restrict__ X,
                            const float* __restrict__ W,
                            float* __restrict__ Y) {
    __shared__ float w_lds[K * HID];
    for (int idx = threadIdx.x; idx < K * HID; idx += blockDim.x)
        w_lds[idx] = W[idx];
    __syncthreads();
    int wave = threadIdx.x >> 6;
    int lane = threadIdx.x & 63;
    int row0 = (blockIdx.x * 4 + wave) * 4;
    if (row0 >= NN) return;
    const float4* xa4 = (const float4*)(X + (size_t)(row0 + 0) * K);
    const float4* xb4 = (const float4*)(X + (size_t)(row0 + 1) * K);
    const float4* xc4 = (const float4*)(X + (size_t)(row0 + 2) * K);
    const float4* xd4 = (const float4*)(X + (size_t)(row0 + 3) * K);
    float acc0 = 0.f, acc1 = 0.f, acc2 = 0.f, acc3 = 0.f;
#pragma unroll
    for (int k4 = 0; k4 < K / 4; ++k4) {
        float4 xa = xa4[k4], xb = xb4[k4], xc = xc4[k4], xd = xd4[k4];
        float w0 = w_lds[(k4 * 4 + 0) * HID + lane];
        float w1 = w_lds[(k4 * 4 + 1) * HID + lane];
        float w2 = w_lds[(k4 * 4 + 2) * HID + lane];
        float w3 = w_lds[(k4 * 4 + 3) * HID + lane];
        acc0 += xa.x * w0 + xa.y * w1 + xa.z * w2 + xa.w * w3;
        acc1 += xb.x * w0 + xb.y * w1 + xb.z * w2 + xb.w * w3;
        acc2 += xc.x * w0 + xc.y * w1 + xc.z * w2 + xc.w * w3;
        acc3 += xd.x * w0 + xd.y * w1 + xd.z * w2 + xd.w * w3;
    }
    Y[(size_t)(row0 + 0) * HID + lane] = acc0;
    Y[(size_t)(row0 + 1) * HID + lane] = acc1;
    Y[(size_t)(row0 + 2) * HID + lane] = acc2;
    Y[(size_t)(row0 + 3) * HID + lane] = acc3;
}

// OUT[node] = act( sum_e w*HW[src] + dis^2*HW[node] + bias )   (1 wave/node)
template <bool RELU>
__global__ void gather_kernel(const int2* __restrict__ csr,
                              const int* __restrict__ offs,
                              const int* __restrict__ indeg,
                              const float* __restrict__ dis,
                              const float* __restrict__ HW,
                              const float* __restrict__ bias,
                              float* __restrict__ OUT) {
    int node = blockIdx.x * 4 + (threadIdx.x >> 6);
    int lane = threadIdx.x & 63;
    if (node >= NN) return;
    int start = offs[node];
    int n = indeg[node];
    float d = dis[node];
    float a0 = d * d * HW[(size_t)node * HID + lane];
    float a1 = 0.f, a2 = 0.f, a3 = 0.f;
    int j = 0;
    for (; j + 4 <= n; j += 4) {
        int2 r0 = csr[start + j + 0];
        int2 r1 = csr[start + j + 1];
        int2 r2 = csr[start + j + 2];
        int2 r3 = csr[start + j + 3];
        a0 += __int_as_float(r0.y) * HW[(size_t)r0.x * HID + lane];
        a1 += __int_as_float(r1.y) * HW[(size_t)r1.x * HID + lane];
        a2 += __int_as_float(r2.y) * HW[(size_t)r2.x * HID + lane];
        a3 += __int_as_float(r3.y) * HW[(size_t)r3.x * HID + lane];
    }
    for (; j < n; ++j) {
        int2 r = csr[start + j];
        a0 += __int_as_float(r.y) * HW[(size_t)r.x * HID + lane];
    }
    float v = (a0 + a1) + (a2 + a3) + bias[lane];
    OUT[(size_t)node * HID + lane] = RELU ? fmaxf(v, 0.0f) : v;
}

// gstart[g] = lower_bound(batch, g)   (batch sorted); gstart[NG] = NN
__global__ void gbounds_kernel(const int* __restrict__ batch, int* __restrict__ gstart) {
    int g = blockIdx.x * blockDim.x + threadIdx.x;
    if (g > NG) return;
    int lo = 0, hi = NN;
    while (lo < hi) {
        int mid = (lo + hi) >> 1;
        if (batch[mid] < g) lo = mid + 1; else hi = mid;
    }
    gstart[g] = lo;
}

// out[g] = (mean of H rows in [gstart[g],gstart[g+1])) . Wlin + blin  (4 waves/graph)
__global__ void pool_head_kernel(const float* __restrict__ H,
                                 const int* __restrict__ gstart,
                                 const float* __restrict__ Wlin,
                                 const float* __restrict__ blin,
                                 float* __restrict__ out) {
    __shared__ float part[4];
    int g = blockIdx.x;
    int lane = threadIdx.x & 63;
    int wv = threadIdx.x >> 6;
    int s = gstart[g], e = gstart[g + 1];
    float wl = Wlin[lane];
    float a = 0.f;
    for (int i = s + wv; i < e; i += 4) a += H[(size_t)i * HID + lane];
    float v = a * wl;
    for (int off = 32; off > 0; off >>= 1) v += __shfl_down(v, off, 64);
    if (lane == 0) part[wv] = v;
    __syncthreads();
    if (threadIdx.x == 0) {
        float t = part[0] + part[1] + part[2] + part[3];
        out[g] = t / fmaxf((float)(e - s), 1.0f) + blin[0];
    }
}

extern "C" void kernel_launch(void* const* d_in, const int* in_sizes, int n_in,
                              void* d_out, int out_size, void* d_ws, size_t ws_size,
                              hipStream_t stream) {
    const float* x     = (const float*)d_in[0];
    const int*   ei    = (const int*)d_in[1];
    const float* ea    = (const float*)d_in[2];
    const int*   batch = (const int*)d_in[3];
    const float* W1    = (const float*)d_in[4];
    const float* b1    = (const float*)d_in[5];
    const float* W2    = (const float*)d_in[6];
    const float* b2    = (const float*)d_in[7];
    const float* Wlin  = (const float*)d_in[8];
    const float* blin  = (const float*)d_in[9];
    float*       out   = (float*)d_out;

    char* ws = (char*)d_ws;
    auto alloc = [&](size_t bytes) {
        void* p = (void*)ws;
        ws += (bytes + 255) / 256 * 256;
        return p;
    };
    float* dis    = (float*)alloc((size_t)NN * 4);
    int*   indeg  = (int*)alloc((size_t)NN * 4);
    int*   offs   = (int*)alloc((size_t)NN * 4);
    int*   csum   = (int*)alloc((size_t)NCH * 4);
    int*   coff   = (int*)alloc((size_t)NCH * 4);
    int*   pcnt   = (int*)alloc((size_t)NBK * EBLK * 4);
    int*   tot    = (int*)alloc((size_t)NBK * 4);
    int*   bbase  = (int*)alloc((size_t)(NBK + 1) * 4);
    int*   gstart = (int*)alloc((size_t)(NG + 1) * 4);
    int2*  recs   = (int2*)alloc((size_t)NE * 8);   // bucket-grouped; dead after sort2
    int2*  csr    = (int2*)alloc((size_t)NE * 8);   // node-grouped
    float* B      = (float*)alloc((size_t)NN * HID * 4);
    float* A      = (float*)recs;                   // hw1/hw2 alias recs (dead by gemm1)

    // two-level bucket sort of edges by dst (no global atomics)
    cnt_kernel<<<EBLK, 256, 0, stream>>>(ei, pcnt);
    bscan_kernel<<<NBK, EBLK, 0, stream>>>(pcnt, tot);
    tscan_kernel<<<1, 512, 0, stream>>>(tot, bbase);
    scatter_kernel<<<EBLK, 256, 0, stream>>>(ei, ea, pcnt, bbase, recs);
    binfo_kernel<<<NBK, 256, 0, stream>>>(recs, bbase, indeg, dis);
    chunksum_kernel<<<NCH, 256, 0, stream>>>(indeg, csum);
    scanchunks_kernel<<<1, 128, 0, stream>>>(csum, coff);
    chunkscan_kernel<<<NCH, CHUNK, 0, stream>>>(indeg, coff, offs);
    sort2_kernel<<<NBK, 256, 0, stream>>>(recs, bbase, dis, offs, csr);

    // conv1: h1 = relu(gather(x@W1) + self + b1)     (gemm1 overwrites recs)
    gemm_kernel<IN_DIM><<<(NN + 15) / 16, 256, 0, stream>>>(x, W1, A);
    gather_kernel<true><<<(NN + 3) / 4, 256, 0, stream>>>(csr, offs, indeg, dis, A, b1, B);

    // conv2: h2 = gather(h1@W2) + self + b2
    gemm_kernel<HID><<<(NN + 15) / 16, 256, 0, stream>>>(B, W2, A);
    gather_kernel<false><<<(NN + 3) / 4, 256, 0, stream>>>(csr, offs, indeg, dis, A, b2, B);

    // mean-pool per sorted-contiguous graph range + head
    gbounds_kernel<<<(NG + 256) / 256, 256, 0, stream>>>(batch, gstart);
    pool_head_kernel<<<NG, 256, 0, stream>>>(B, gstart, Wlin, blin, out);
}

// Round 8
// 247.103 us; speedup vs baseline: 6.8228x; 1.2338x over previous
//
#include <hip/hip_runtime.h>

#define NN 50000
#define NE 1600000
#define NG 512
#define IN_DIM 128
#define HID 64

#define NB 128                       // nodes per bucket
#define NBK ((NN + NB - 1) / NB)     // 391 buckets
#define EBLK 512                     // edge-pass blocks
#define EPB (NE / EBLK)              // 3125 edges per block
#define CHUNK 512
#define NCH ((NN + CHUNK - 1) / CHUNK)   // 98

// ---- pass 1: per-block coarse histogram of dst>>7 ----
__global__ void cnt_kernel(const int* __restrict__ ei, int* __restrict__ pcnt) {
    __shared__ int h[NBK];
    for (int i = threadIdx.x; i < NBK; i += blockDim.x) h[i] = 0;
    __syncthreads();
    int base = blockIdx.x * EPB;
    for (int e = base + threadIdx.x; e < base + EPB; e += blockDim.x)
        atomicAdd(&h[ei[NE + e] >> 7], 1);
    __syncthreads();
    for (int i = threadIdx.x; i < NBK; i += blockDim.x)
        pcnt[(size_t)i * EBLK + blockIdx.x] = h[i];
}

// ---- pass 2a: per-bucket exclusive scan over the EBLK partials ----
__global__ void bscan_kernel(int* __restrict__ pcnt, int* __restrict__ tot) {
    __shared__ int s[EBLK];
    int k = blockIdx.x, t = threadIdx.x;
    int v = pcnt[(size_t)k * EBLK + t];
    s[t] = v;
    __syncthreads();
    for (int off = 1; off < EBLK; off <<= 1) {
        int add = (t >= off) ? s[t - off] : 0;
        __syncthreads();
        s[t] += add;
        __syncthreads();
    }
    pcnt[(size_t)k * EBLK + t] = s[t] - v;   // exclusive within bucket
    if (t == EBLK - 1) tot[k] = s[t];
}

// ---- pass 2b: exclusive scan of bucket totals -> bbase[0..NBK] ----
__global__ void tscan_kernel(const int* __restrict__ tot, int* __restrict__ bbase) {
    __shared__ int s[512];
    int t = threadIdx.x;
    int v = (t < NBK) ? tot[t] : 0;
    s[t] = v;
    __syncthreads();
    for (int off = 1; off < 512; off <<= 1) {
        int add = (t >= off) ? s[t - off] : 0;
        __syncthreads();
        s[t] += add;
        __syncthreads();
    }
    if (t < NBK) bbase[t] = s[t] - v;
    if (t == NBK - 1) bbase[NBK] = s[t];
}

// ---- pass 3: scatter records {dl:7|src:17, ea} grouped by bucket ----
__global__ void scatter_kernel(const int* __restrict__ ei, const float* __restrict__ ea,
                               const int* __restrict__ pcnt, const int* __restrict__ bbase,
                               int2* __restrict__ recs) {
    __shared__ int curs[NBK];
    int b = blockIdx.x;
    for (int i = threadIdx.x; i < NBK; i += blockDim.x)
        curs[i] = bbase[i] + pcnt[(size_t)i * EBLK + b];
    __syncthreads();
    int base = b * EPB;
    for (int e = base + threadIdx.x; e < base + EPB; e += blockDim.x) {
        int dst = ei[NE + e];
        int src = ei[e];
        int k = dst >> 7;
        int pos = atomicAdd(&curs[k], 1);
        recs[pos] = make_int2(((dst & 127) << 17) | src, __float_as_int(ea[e]));
    }
}

// ---- per-bucket: indeg[node], dis[node] = rsqrt(1 + weighted deg) ----
__global__ void binfo_kernel(const int2* __restrict__ recs, const int* __restrict__ bbase,
                             int* __restrict__ indeg, float* __restrict__ dis) {
    __shared__ float deg[NB];
    __shared__ int cnt[NB];
    int k = blockIdx.x;
    int lo = k * NB;
    int nLoc = min(NB, NN - lo);
    for (int i = threadIdx.x; i < nLoc; i += blockDim.x) { deg[i] = 0.f; cnt[i] = 0; }
    __syncthreads();
    int start = bbase[k], end = bbase[k + 1];
    for (int e = start + threadIdx.x; e < end; e += blockDim.x) {
        int2 r = recs[e];
        int dl = r.x >> 17;
        atomicAdd(&deg[dl], __int_as_float(r.y));
        atomicAdd(&cnt[dl], 1);
    }
    __syncthreads();
    for (int i = threadIdx.x; i < nLoc; i += blockDim.x) {
        indeg[lo + i] = cnt[i];
        dis[lo + i] = rsqrtf(deg[i] + 1.0f);
    }
}

// ---- 3-phase exclusive scan of indeg -> offs ----
__global__ void chunksum_kernel(const int* __restrict__ cnt, int* __restrict__ csum) {
    __shared__ int s[256];
    int b = blockIdx.x, t = threadIdx.x;
    int base = b * CHUNK;
    int v = 0;
    for (int i = t; i < CHUNK; i += 256) {
        int idx = base + i;
        if (idx < NN) v += cnt[idx];
    }
    s[t] = v;
    __syncthreads();
    for (int off = 128; off > 0; off >>= 1) {
        if (t < off) s[t] += s[t + off];
        __syncthreads();
    }
    if (t == 0) csum[b] = s[0];
}

__global__ void scanchunks_kernel(const int* __restrict__ csum, int* __restrict__ coff) {
    __shared__ int s[128];
    int t = threadIdx.x;
    int v = (t < NCH) ? csum[t] : 0;
    s[t] = v;
    __syncthreads();
    for (int off = 1; off < 128; off <<= 1) {
        int add = (t >= off) ? s[t - off] : 0;
        __syncthreads();
        s[t] += add;
        __syncthreads();
    }
    if (t < NCH) coff[t] = s[t] - v;   // exclusive
}

__global__ void chunkscan_kernel(const int* __restrict__ cnt,
                                 const int* __restrict__ coff,
                                 int* __restrict__ offs) {
    __shared__ int s[CHUNK];
    int b = blockIdx.x, t = threadIdx.x;
    int idx = b * CHUNK + t;
    int v = (idx < NN) ? cnt[idx] : 0;
    s[t] = v;
    __syncthreads();
    for (int off = 1; off < CHUNK; off <<= 1) {
        int add = (t >= off) ? s[t - off] : 0;
        __syncthreads();
        s[t] += add;
        __syncthreads();
    }
    if (idx < NN) offs[idx] = coff[b] + s[t] - v;
}

// ---- level-2 sort: bucket records -> exact per-node CSR {src, norm} ----
__global__ void sort2_kernel(const int2* __restrict__ recs, const int* __restrict__ bbase,
                             const float* __restrict__ dis, const int* __restrict__ offs,
                             int2* __restrict__ csr) {
    __shared__ int curs[NB];
    __shared__ float wdst[NB];
    int k = blockIdx.x;
    int lo = k * NB;
    int nLoc = min(NB, NN - lo);
    for (int i = threadIdx.x; i < nLoc; i += blockDim.x) {
        curs[i] = offs[lo + i];
        wdst[i] = dis[lo + i];
    }
    __syncthreads();
    int start = bbase[k], end = bbase[k + 1];
    for (int e = start + threadIdx.x; e < end; e += blockDim.x) {
        int2 r = recs[e];
        int src = r.x & 0x1FFFF;
        int dl = r.x >> 17;
        float w = dis[src] * __int_as_float(r.y) * wdst[dl];
        int pos = atomicAdd(&curs[dl], 1);
        csr[pos] = make_int2(src, __float_as_int(w));
    }
}

// ---- tiled GEMM: 64 rows x 64 cols per block, X transposed in LDS ----
// Y[n,HID] = X[n,K] @ W[K,HID]. Each thread: 4x4 register tile.
template <int K>
__global__ __launch_bounds__(256) void gemm_kernel(const float* __restrict__ X,
                                                   const float* __restrict__ W,
                                                   float* __restrict__ Y) {
    __shared__ float w_lds[K * HID];     // [K][64]
    __shared__ float x_lds[K][65];       // transposed [k][row], pad 65
    int tid = threadIdx.x;
    int rowbase = blockIdx.x * 64;
    for (int i = tid; i < K * HID; i += 256) w_lds[i] = W[i];
    // stage X: coalesced float4 reads, transposed scatter to LDS
    for (int i = tid; i < 16 * K; i += 256) {
        int row = i / (K / 4);
        int k4 = i % (K / 4);
        int r = rowbase + row;
        float4 v = (r < NN) ? ((const float4*)(X + (size_t)r * K))[k4]
                            : make_float4(0.f, 0.f, 0.f, 0.f);
        x_lds[k4 * 4 + 0][row] = v.x;
        x_lds[k4 * 4 + 1][row] = v.y;
        x_lds[k4 * 4 + 2][row] = v.z;
        x_lds[k4 * 4 + 3][row] = v.w;
    }
    __syncthreads();
    int c0 = (tid & 15) * 4;
    int r0 = (tid >> 4) * 4;
    float acc[4][4] = {};
#pragma unroll 4
    for (int k = 0; k < K; ++k) {
        float x0 = x_lds[k][r0 + 0];
        float x1 = x_lds[k][r0 + 1];
        float x2 = x_lds[k][r0 + 2];
        float x3 = x_lds[k][r0 + 3];
        float4 wv = *(const float4*)&w_lds[k * HID + c0];
        acc[0][0] += x0 * wv.x; acc[0][1] += x0 * wv.y; acc[0][2] += x0 * wv.z; acc[0][3] += x0 * wv.w;
        acc[1][0] += x1 * wv.x; acc[1][1] += x1 * wv.y; acc[1][2] += x1 * wv.z; acc[1][3] += x1 * wv.w;
        acc[2][0] += x2 * wv.x; acc[2][1] += x2 * wv.y; acc[2][2] += x2 * wv.z; acc[2][3] += x2 * wv.w;
        acc[3][0] += x3 * wv.x; acc[3][1] += x3 * wv.y; acc[3][2] += x3 * wv.z; acc[3][3] += x3 * wv.w;
    }
#pragma unroll
    for (int i = 0; i < 4; ++i) {
        int r = rowbase + r0 + i;
        if (r < NN)
            *(float4*)&Y[(size_t)r * HID + c0] =
                make_float4(acc[i][0], acc[i][1], acc[i][2], acc[i][3]);
    }
}

// OUT[node] = act( sum_e w*HW[src] + dis^2*HW[node] + bias )   (1 wave/node)
template <bool RELU>
__global__ void gather_kernel(const int2* __restrict__ csr,
                              const int* __restrict__ offs,
                              const int* __restrict__ indeg,
                              const float* __restrict__ dis,
                              const float* __restrict__ HW,
                              const float* __restrict__ bias,
                              float* __restrict__ OUT) {
    int node = blockIdx.x * 4 + (threadIdx.x >> 6);
    int lane = threadIdx.x & 63;
    if (node >= NN) return;
    int start = offs[node];
    int n = indeg[node];
    float d = dis[node];
    float a0 = d * d * HW[(size_t)node * HID + lane];
    float a1 = 0.f, a2 = 0.f, a3 = 0.f;
    int j = 0;
    for (; j + 4 <= n; j += 4) {
        int2 r0 = csr[start + j + 0];
        int2 r1 = csr[start + j + 1];
        int2 r2 = csr[start + j + 2];
        int2 r3 = csr[start + j + 3];
        a0 += __int_as_float(r0.y) * HW[(size_t)r0.x * HID + lane];
        a1 += __int_as_float(r1.y) * HW[(size_t)r1.x * HID + lane];
        a2 += __int_as_float(r2.y) * HW[(size_t)r2.x * HID + lane];
        a3 += __int_as_float(r3.y) * HW[(size_t)r3.x * HID + lane];
    }
    for (; j < n; ++j) {
        int2 r = csr[start + j];
        a0 += __int_as_float(r.y) * HW[(size_t)r.x * HID + lane];
    }
    float v = (a0 + a1) + (a2 + a3) + bias[lane];
    OUT[(size_t)node * HID + lane] = RELU ? fmaxf(v, 0.0f) : v;
}

// gstart[g] = lower_bound(batch, g)   (batch sorted); gstart[NG] = NN
__global__ void gbounds_kernel(const int* __restrict__ batch, int* __restrict__ gstart) {
    int g = blockIdx.x * blockDim.x + threadIdx.x;
    if (g > NG) return;
    int lo = 0, hi = NN;
    while (lo < hi) {
        int mid = (lo + hi) >> 1;
        if (batch[mid] < g) lo = mid + 1; else hi = mid;
    }
    gstart[g] = lo;
}

// out[g] = (mean of H rows in [gstart[g],gstart[g+1])) . Wlin + blin  (4 waves/graph)
__global__ void pool_head_kernel(const float* __restrict__ H,
                                 const int* __restrict__ gstart,
                                 const float* __restrict__ Wlin,
                                 const float* __restrict__ blin,
                                 float* __restrict__ out) {
    __shared__ float part[4];
    int g = blockIdx.x;
    int lane = threadIdx.x & 63;
    int wv = threadIdx.x >> 6;
    int s = gstart[g], e = gstart[g + 1];
    float wl = Wlin[lane];
    float a = 0.f;
    for (int i = s + wv; i < e; i += 4) a += H[(size_t)i * HID + lane];
    float v = a * wl;
    for (int off = 32; off > 0; off >>= 1) v += __shfl_down(v, off, 64);
    if (lane == 0) part[wv] = v;
    __syncthreads();
    if (threadIdx.x == 0) {
        float t = part[0] + part[1] + part[2] + part[3];
        out[g] = t / fmaxf((float)(e - s), 1.0f) + blin[0];
    }
}

extern "C" void kernel_launch(void* const* d_in, const int* in_sizes, int n_in,
                              void* d_out, int out_size, void* d_ws, size_t ws_size,
                              hipStream_t stream) {
    const float* x     = (const float*)d_in[0];
    const int*   ei    = (const int*)d_in[1];
    const float* ea    = (const float*)d_in[2];
    const int*   batch = (const int*)d_in[3];
    const float* W1    = (const float*)d_in[4];
    const float* b1    = (const float*)d_in[5];
    const float* W2    = (const float*)d_in[6];
    const float* b2    = (const float*)d_in[7];
    const float* Wlin  = (const float*)d_in[8];
    const float* blin  = (const float*)d_in[9];
    float*       out   = (float*)d_out;

    char* ws = (char*)d_ws;
    auto alloc = [&](size_t bytes) {
        void* p = (void*)ws;
        ws += (bytes + 255) / 256 * 256;
        return p;
    };
    float* dis    = (float*)alloc((size_t)NN * 4);
    int*   indeg  = (int*)alloc((size_t)NN * 4);
    int*   offs   = (int*)alloc((size_t)NN * 4);
    int*   csum   = (int*)alloc((size_t)NCH * 4);
    int*   coff   = (int*)alloc((size_t)NCH * 4);
    int*   pcnt   = (int*)alloc((size_t)NBK * EBLK * 4);
    int*   tot    = (int*)alloc((size_t)NBK * 4);
    int*   bbase  = (int*)alloc((size_t)(NBK + 1) * 4);
    int*   gstart = (int*)alloc((size_t)(NG + 1) * 4);
    int2*  recs   = (int2*)alloc((size_t)NE * 8);   // bucket-grouped; dead after sort2
    int2*  csr    = (int2*)alloc((size_t)NE * 8);   // node-grouped
    float* B      = (float*)alloc((size_t)NN * HID * 4);
    float* A      = (float*)recs;                   // hw1/hw2 alias recs (dead by gemm1)

    // two-level bucket sort of edges by dst (no global atomics)
    cnt_kernel<<<EBLK, 256, 0, stream>>>(ei, pcnt);
    bscan_kernel<<<NBK, EBLK, 0, stream>>>(pcnt, tot);
    tscan_kernel<<<1, 512, 0, stream>>>(tot, bbase);
    scatter_kernel<<<EBLK, 256, 0, stream>>>(ei, ea, pcnt, bbase, recs);
    binfo_kernel<<<NBK, 256, 0, stream>>>(recs, bbase, indeg, dis);
    chunksum_kernel<<<NCH, 256, 0, stream>>>(indeg, csum);
    scanchunks_kernel<<<1, 128, 0, stream>>>(csum, coff);
    chunkscan_kernel<<<NCH, CHUNK, 0, stream>>>(indeg, coff, offs);
    sort2_kernel<<<NBK, 256, 0, stream>>>(recs, bbase, dis, offs, csr);

    // conv1: h1 = relu(gather(x@W1) + self + b1)     (gemm1 overwrites recs)
    gemm_kernel<IN_DIM><<<(NN + 63) / 64, 256, 0, stream>>>(x, W1, A);
    gather_kernel<true><<<(NN + 3) / 4, 256, 0, stream>>>(csr, offs, indeg, dis, A, b1, B);

    // conv2: h2 = gather(h1@W2) + self + b2
    gemm_kernel<HID><<<(NN + 63) / 64, 256, 0, stream>>>(B, W2, A);
    gather_kernel<false><<<(NN + 3) / 4, 256, 0, stream>>>(csr, offs, indeg, dis, A, b2, B);

    // mean-pool per sorted-contiguous graph range + head
    gbounds_kernel<<<(NG + 256) / 256, 256, 0, stream>>>(batch, gstart);
    pool_head_kernel<<<NG, 256, 0, stream>>>(B, gstart, Wlin, blin, out);
}

// Round 9
// 223.340 us; speedup vs baseline: 7.5487x; 1.1064x over previous
//
#include <hip/hip_runtime.h>

#define NN 50000
#define NE 1600000
#define NG 512
#define IN_DIM 128
#define HID 64

#define NB 128                       // nodes per bucket
#define NBK ((NN + NB - 1) / NB)     // 391 buckets
#define EBLK 512                     // edge-pass blocks
#define EPB (NE / EBLK)              // 3125 edges per block

typedef unsigned short ushort_t;
typedef unsigned int uint_t;

// float -> bf16 (RNE)
static __device__ __forceinline__ ushort_t f2bf(float f) {
    uint_t u = __float_as_uint(f);
    u += 0x7FFFu + ((u >> 16) & 1u);
    return (ushort_t)(u >> 16);
}
// bf16 -> float
static __device__ __forceinline__ float bf2f(ushort_t h) {
    return __uint_as_float((uint_t)h << 16);
}

// ---- pass 1: per-block coarse histogram of dst>>7 ----
__global__ void cnt_kernel(const int* __restrict__ ei, int* __restrict__ pcnt) {
    __shared__ int h[NBK];
    for (int i = threadIdx.x; i < NBK; i += blockDim.x) h[i] = 0;
    __syncthreads();
    int base = blockIdx.x * EPB;
    for (int e = base + threadIdx.x; e < base + EPB; e += blockDim.x)
        atomicAdd(&h[ei[NE + e] >> 7], 1);
    __syncthreads();
    for (int i = threadIdx.x; i < NBK; i += blockDim.x)
        pcnt[(size_t)i * EBLK + blockIdx.x] = h[i];
}

// ---- pass 2a: per-bucket exclusive scan over the EBLK partials ----
__global__ void bscan_kernel(int* __restrict__ pcnt, int* __restrict__ tot) {
    __shared__ int s[EBLK];
    int k = blockIdx.x, t = threadIdx.x;
    int v = pcnt[(size_t)k * EBLK + t];
    s[t] = v;
    __syncthreads();
    for (int off = 1; off < EBLK; off <<= 1) {
        int add = (t >= off) ? s[t - off] : 0;
        __syncthreads();
        s[t] += add;
        __syncthreads();
    }
    pcnt[(size_t)k * EBLK + t] = s[t] - v;   // exclusive within bucket
    if (t == EBLK - 1) tot[k] = s[t];
}

// ---- pass 2b: exclusive scan of bucket totals -> bbase[0..NBK] ----
__global__ void tscan_kernel(const int* __restrict__ tot, int* __restrict__ bbase) {
    __shared__ int s[512];
    int t = threadIdx.x;
    int v = (t < NBK) ? tot[t] : 0;
    s[t] = v;
    __syncthreads();
    for (int off = 1; off < 512; off <<= 1) {
        int add = (t >= off) ? s[t - off] : 0;
        __syncthreads();
        s[t] += add;
        __syncthreads();
    }
    if (t < NBK) bbase[t] = s[t] - v;
    if (t == NBK - 1) bbase[NBK] = s[t];
}

// ---- pass 3: scatter records {dl:7|src:17, ea} grouped by bucket ----
__global__ void scatter_kernel(const int* __restrict__ ei, const float* __restrict__ ea,
                               const int* __restrict__ pcnt, const int* __restrict__ bbase,
                               int2* __restrict__ recs) {
    __shared__ int curs[NBK];
    int b = blockIdx.x;
    for (int i = threadIdx.x; i < NBK; i += blockDim.x)
        curs[i] = bbase[i] + pcnt[(size_t)i * EBLK + b];
    __syncthreads();
    int base = b * EPB;
    for (int e = base + threadIdx.x; e < base + EPB; e += blockDim.x) {
        int dst = ei[NE + e];
        int src = ei[e];
        int k = dst >> 7;
        int pos = atomicAdd(&curs[k], 1);
        recs[pos] = make_int2(((dst & 127) << 17) | src, __float_as_int(ea[e]));
    }
}

// ---- merged bucket pass: deg/indeg + in-bucket scan -> offs, dis; then
//      scatter bucket recs to exact per-node CSR {src, ea*dis[dst]} ----
__global__ void binfo2_kernel(const int2* __restrict__ recs, const int* __restrict__ bbase,
                              int* __restrict__ indeg, float* __restrict__ dis,
                              int* __restrict__ offs, int2* __restrict__ csr) {
    __shared__ float deg[NB];
    __shared__ int cnt[NB];
    __shared__ int sc[NB];
    __shared__ int curs[NB];
    __shared__ float wdst[NB];
    int k = blockIdx.x;
    int lo = k * NB;
    int nLoc = min(NB, NN - lo);
    int tid = threadIdx.x;
    for (int i = tid; i < nLoc; i += blockDim.x) { deg[i] = 0.f; cnt[i] = 0; }
    __syncthreads();
    int start = bbase[k], end = bbase[k + 1];
    for (int e = start + tid; e < end; e += blockDim.x) {
        int2 r = recs[e];
        int dl = r.x >> 17;
        atomicAdd(&deg[dl], __int_as_float(r.y));
        atomicAdd(&cnt[dl], 1);
    }
    __syncthreads();
    for (int i = tid; i < nLoc; i += blockDim.x) {
        float d = rsqrtf(deg[i] + 1.0f);
        wdst[i] = d;
        dis[lo + i] = d;
        indeg[lo + i] = cnt[i];
    }
    if (tid < NB) sc[tid] = (tid < nLoc) ? cnt[tid] : 0;
    __syncthreads();
    // inclusive scan over 128 bins
    for (int off = 1; off < NB; off <<= 1) {
        int add = (tid < NB && tid >= off) ? sc[tid - off] : 0;
        __syncthreads();
        if (tid < NB) sc[tid] += add;
        __syncthreads();
    }
    if (tid < nLoc) {
        int ex = start + sc[tid] - cnt[tid];   // exclusive position
        offs[lo + tid] = ex;
        curs[tid] = ex;
    }
    __syncthreads();
    for (int e = start + tid; e < end; e += blockDim.x) {
        int2 r = recs[e];
        int src = r.x & 0x1FFFF;
        int dl = r.x >> 17;
        float pw = __int_as_float(r.y) * wdst[dl];   // ea * dis[dst]
        int pos = atomicAdd(&curs[dl], 1);
        csr[pos] = make_int2(src, __float_as_int(pw));
    }
}

// ---- tiled GEMM: 64 rows x 64 cols per block, X transposed in LDS ----
// Yb[n,HID] = bf16( X[n,K] @ W[K,HID] ). Each thread: 4x4 register tile.
template <int K>
__global__ __launch_bounds__(256) void gemm_kernel(const float* __restrict__ X,
                                                   const float* __restrict__ W,
                                                   ushort_t* __restrict__ Yb) {
    __shared__ float w_lds[K * HID];     // [K][64]
    __shared__ float x_lds[K][65];       // transposed [k][row], pad 65
    int tid = threadIdx.x;
    int rowbase = blockIdx.x * 64;
    for (int i = tid; i < K * HID; i += 256) w_lds[i] = W[i];
    for (int i = tid; i < 16 * K; i += 256) {
        int row = i / (K / 4);
        int k4 = i % (K / 4);
        int r = rowbase + row;
        float4 v = (r < NN) ? ((const float4*)(X + (size_t)r * K))[k4]
                            : make_float4(0.f, 0.f, 0.f, 0.f);
        x_lds[k4 * 4 + 0][row] = v.x;
        x_lds[k4 * 4 + 1][row] = v.y;
        x_lds[k4 * 4 + 2][row] = v.z;
        x_lds[k4 * 4 + 3][row] = v.w;
    }
    __syncthreads();
    int c0 = (tid & 15) * 4;
    int r0 = (tid >> 4) * 4;
    float acc[4][4] = {};
#pragma unroll 4
    for (int k = 0; k < K; ++k) {
        float x0 = x_lds[k][r0 + 0];
        float x1 = x_lds[k][r0 + 1];
        float x2 = x_lds[k][r0 + 2];
        float x3 = x_lds[k][r0 + 3];
        float4 wv = *(const float4*)&w_lds[k * HID + c0];
        acc[0][0] += x0 * wv.x; acc[0][1] += x0 * wv.y; acc[0][2] += x0 * wv.z; acc[0][3] += x0 * wv.w;
        acc[1][0] += x1 * wv.x; acc[1][1] += x1 * wv.y; acc[1][2] += x1 * wv.z; acc[1][3] += x1 * wv.w;
        acc[2][0] += x2 * wv.x; acc[2][1] += x2 * wv.y; acc[2][2] += x2 * wv.z; acc[2][3] += x2 * wv.w;
        acc[3][0] += x3 * wv.x; acc[3][1] += x3 * wv.y; acc[3][2] += x3 * wv.z; acc[3][3] += x3 * wv.w;
    }
#pragma unroll
    for (int i = 0; i < 4; ++i) {
        int r = rowbase + r0 + i;
        if (r < NN) {
            ushort4 o;
            o.x = f2bf(acc[i][0]); o.y = f2bf(acc[i][1]);
            o.z = f2bf(acc[i][2]); o.w = f2bf(acc[i][3]);
            *(ushort4*)&Yb[(size_t)r * HID + c0] = o;
        }
    }
}

// OUT[node] = act( sum_e dis[src]*pw*HW[src] + dis^2*HW[node] + bias )  (1 wave/node)
template <bool RELU>
__global__ void gather_kernel(const int2* __restrict__ csr,
                              const int* __restrict__ offs,
                              const int* __restrict__ indeg,
                              const float* __restrict__ dis,
                              const ushort_t* __restrict__ HWb,
                              const float* __restrict__ bias,
                              float* __restrict__ OUT) {
    int node = blockIdx.x * 4 + (threadIdx.x >> 6);
    int lane = threadIdx.x & 63;
    if (node >= NN) return;
    int start = offs[node];
    int n = indeg[node];
    float d = dis[node];
    float a0 = d * d * bf2f(HWb[(size_t)node * HID + lane]);
    float a1 = 0.f, a2 = 0.f, a3 = 0.f;
    int j = 0;
    for (; j + 4 <= n; j += 4) {
        int2 r0 = csr[start + j + 0];
        int2 r1 = csr[start + j + 1];
        int2 r2 = csr[start + j + 2];
        int2 r3 = csr[start + j + 3];
        float w0 = dis[r0.x] * __int_as_float(r0.y);
        float w1 = dis[r1.x] * __int_as_float(r1.y);
        float w2 = dis[r2.x] * __int_as_float(r2.y);
        float w3 = dis[r3.x] * __int_as_float(r3.y);
        a0 += w0 * bf2f(HWb[(size_t)r0.x * HID + lane]);
        a1 += w1 * bf2f(HWb[(size_t)r1.x * HID + lane]);
        a2 += w2 * bf2f(HWb[(size_t)r2.x * HID + lane]);
        a3 += w3 * bf2f(HWb[(size_t)r3.x * HID + lane]);
    }
    for (; j < n; ++j) {
        int2 r = csr[start + j];
        a0 += dis[r.x] * __int_as_float(r.y) * bf2f(HWb[(size_t)r.x * HID + lane]);
    }
    float v = (a0 + a1) + (a2 + a3) + bias[lane];
    OUT[(size_t)node * HID + lane] = RELU ? fmaxf(v, 0.0f) : v;
}

// gstart[g] = lower_bound(batch, g)   (batch sorted); gstart[NG] = NN
__global__ void gbounds_kernel(const int* __restrict__ batch, int* __restrict__ gstart) {
    int g = blockIdx.x * blockDim.x + threadIdx.x;
    if (g > NG) return;
    int lo = 0, hi = NN;
    while (lo < hi) {
        int mid = (lo + hi) >> 1;
        if (batch[mid] < g) lo = mid + 1; else hi = mid;
    }
    gstart[g] = lo;
}

// out[g] = (mean of H rows in [gstart[g],gstart[g+1])) . Wlin + blin  (4 waves/graph)
__global__ void pool_head_kernel(const float* __restrict__ H,
                                 const int* __restrict__ gstart,
                                 const float* __restrict__ Wlin,
                                 const float* __restrict__ blin,
                                 float* __restrict__ out) {
    __shared__ float part[4];
    int g = blockIdx.x;
    int lane = threadIdx.x & 63;
    int wv = threadIdx.x >> 6;
    int s = gstart[g], e = gstart[g + 1];
    float wl = Wlin[lane];
    float a = 0.f;
    for (int i = s + wv; i < e; i += 4) a += H[(size_t)i * HID + lane];
    float v = a * wl;
    for (int off = 32; off > 0; off >>= 1) v += __shfl_down(v, off, 64);
    if (lane == 0) part[wv] = v;
    __syncthreads();
    if (threadIdx.x == 0) {
        float t = part[0] + part[1] + part[2] + part[3];
        out[g] = t / fmaxf((float)(e - s), 1.0f) + blin[0];
    }
}

extern "C" void kernel_launch(void* const* d_in, const int* in_sizes, int n_in,
                              void* d_out, int out_size, void* d_ws, size_t ws_size,
                              hipStream_t stream) {
    const float* x     = (const float*)d_in[0];
    const int*   ei    = (const int*)d_in[1];
    const float* ea    = (const float*)d_in[2];
    const int*   batch = (const int*)d_in[3];
    const float* W1    = (const float*)d_in[4];
    const float* b1    = (const float*)d_in[5];
    const float* W2    = (const float*)d_in[6];
    const float* b2    = (const float*)d_in[7];
    const float* Wlin  = (const float*)d_in[8];
    const float* blin  = (const float*)d_in[9];
    float*       out   = (float*)d_out;

    char* ws = (char*)d_ws;
    auto alloc = [&](size_t bytes) {
        void* p = (void*)ws;
        ws += (bytes + 255) / 256 * 256;
        return p;
    };
    float*    dis    = (float*)alloc((size_t)NN * 4);
    int*      indeg  = (int*)alloc((size_t)NN * 4);
    int*      offs   = (int*)alloc((size_t)NN * 4);
    int*      pcnt   = (int*)alloc((size_t)NBK * EBLK * 4);
    int*      tot    = (int*)alloc((size_t)NBK * 4);
    int*      bbase  = (int*)alloc((size_t)(NBK + 1) * 4);
    int*      gstart = (int*)alloc((size_t)(NG + 1) * 4);
    int2*     recs   = (int2*)alloc((size_t)NE * 8);   // bucket-grouped; dead after binfo2
    int2*     csr    = (int2*)alloc((size_t)NE * 8);   // node-grouped {src, ea*dis[dst]}
    float*    B      = (float*)alloc((size_t)NN * HID * 4);
    ushort_t* A      = (ushort_t*)recs;                // bf16 hw1/hw2 alias recs

    // two-level bucket sort of edges by dst (no global atomics)
    cnt_kernel<<<EBLK, 256, 0, stream>>>(ei, pcnt);
    bscan_kernel<<<NBK, EBLK, 0, stream>>>(pcnt, tot);
    tscan_kernel<<<1, 512, 0, stream>>>(tot, bbase);
    scatter_kernel<<<EBLK, 256, 0, stream>>>(ei, ea, pcnt, bbase, recs);
    binfo2_kernel<<<NBK, 256, 0, stream>>>(recs, bbase, indeg, dis, offs, csr);

    // conv1: h1 = relu(gather(bf16(x@W1)) + self + b1)   (gemm1 overwrites recs)
    gemm_kernel<IN_DIM><<<(NN + 63) / 64, 256, 0, stream>>>(x, W1, A);
    gather_kernel<true><<<(NN + 3) / 4, 256, 0, stream>>>(csr, offs, indeg, dis, A, b1, B);

    // conv2: h2 = gather(bf16(h1@W2)) + self + b2
    gemm_kernel<HID><<<(NN + 63) / 64, 256, 0, stream>>>(B, W2, A);
    gather_kernel<false><<<(NN + 3) / 4, 256, 0, stream>>>(csr, offs, indeg, dis, A, b2, B);

    // mean-pool per sorted-contiguous graph range + head
    gbounds_kernel<<<(NG + 256) / 256, 256, 0, stream>>>(batch, gstart);
    pool_head_kernel<<<NG, 256, 0, stream>>>(B, gstart, Wlin, blin, out);
}

// Round 10
// 187.215 us; speedup vs baseline: 9.0053x; 1.1930x over previous
//
#include <hip/hip_runtime.h>

#define NN 50000
#define NE 1600000
#define NG 512
#define IN_DIM 128
#define HID 64

#define NB 128                       // nodes per bucket
#define NBK ((NN + NB - 1) / NB)     // 391 buckets
#define EBLK 512                     // edge-pass blocks
#define EPB (NE / EBLK)              // 3125 edges per block

typedef unsigned short ushort_t;
typedef unsigned int uint_t;

// float -> bf16 (RNE)
static __device__ __forceinline__ ushort_t f2bf(float f) {
    uint_t u = __float_as_uint(f);
    u += 0x7FFFu + ((u >> 16) & 1u);
    return (ushort_t)(u >> 16);
}
// bf16 -> float
static __device__ __forceinline__ float bf2f(ushort_t h) {
    return __uint_as_float((uint_t)h << 16);
}

// ---- pass 1: per-block coarse histogram of dst>>7 ----
__global__ void cnt_kernel(const int* __restrict__ ei, int* __restrict__ pcnt) {
    __shared__ int h[NBK];
    for (int i = threadIdx.x; i < NBK; i += blockDim.x) h[i] = 0;
    __syncthreads();
    int base = blockIdx.x * EPB;
    for (int e = base + threadIdx.x; e < base + EPB; e += blockDim.x)
        atomicAdd(&h[ei[NE + e] >> 7], 1);
    __syncthreads();
    for (int i = threadIdx.x; i < NBK; i += blockDim.x)
        pcnt[(size_t)i * EBLK + blockIdx.x] = h[i];
}

// ---- pass 2a: per-bucket exclusive scan over the EBLK partials ----
__global__ void bscan_kernel(int* __restrict__ pcnt, int* __restrict__ tot) {
    __shared__ int s[EBLK];
    int k = blockIdx.x, t = threadIdx.x;
    int v = pcnt[(size_t)k * EBLK + t];
    s[t] = v;
    __syncthreads();
    for (int off = 1; off < EBLK; off <<= 1) {
        int add = (t >= off) ? s[t - off] : 0;
        __syncthreads();
        s[t] += add;
        __syncthreads();
    }
    pcnt[(size_t)k * EBLK + t] = s[t] - v;   // exclusive within bucket
    if (t == EBLK - 1) tot[k] = s[t];
}

// ---- pass 2b: exclusive scan of bucket totals -> bbase[0..NBK] ----
__global__ void tscan_kernel(const int* __restrict__ tot, int* __restrict__ bbase) {
    __shared__ int s[512];
    int t = threadIdx.x;
    int v = (t < NBK) ? tot[t] : 0;
    s[t] = v;
    __syncthreads();
    for (int off = 1; off < 512; off <<= 1) {
        int add = (t >= off) ? s[t - off] : 0;
        __syncthreads();
        s[t] += add;
        __syncthreads();
    }
    if (t < NBK) bbase[t] = s[t] - v;
    if (t == NBK - 1) bbase[NBK] = s[t];
}

// ---- pass 3: scatter records {dl:7|src:17, ea} grouped by bucket ----
__global__ void scatter_kernel(const int* __restrict__ ei, const float* __restrict__ ea,
                               const int* __restrict__ pcnt, const int* __restrict__ bbase,
                               int2* __restrict__ recs) {
    __shared__ int curs[NBK];
    int b = blockIdx.x;
    for (int i = threadIdx.x; i < NBK; i += blockDim.x)
        curs[i] = bbase[i] + pcnt[(size_t)i * EBLK + b];
    __syncthreads();
    int base = b * EPB;
    for (int e = base + threadIdx.x; e < base + EPB; e += blockDim.x) {
        int dst = ei[NE + e];
        int src = ei[e];
        int k = dst >> 7;
        int pos = atomicAdd(&curs[k], 1);
        recs[pos] = make_int2(((dst & 127) << 17) | src, __float_as_int(ea[e]));
    }
}

// ---- merged bucket pass: deg/indeg + in-bucket scan -> offs, dis; then
//      scatter bucket recs to exact per-node CSR {src, ea*dis[dst]} ----
__global__ void binfo2_kernel(const int2* __restrict__ recs, const int* __restrict__ bbase,
                              int* __restrict__ indeg, float* __restrict__ dis,
                              int* __restrict__ offs, int2* __restrict__ csr) {
    __shared__ float deg[NB];
    __shared__ int cnt[NB];
    __shared__ int sc[NB];
    __shared__ int curs[NB];
    __shared__ float wdst[NB];
    int k = blockIdx.x;
    int lo = k * NB;
    int nLoc = min(NB, NN - lo);
    int tid = threadIdx.x;
    for (int i = tid; i < nLoc; i += blockDim.x) { deg[i] = 0.f; cnt[i] = 0; }
    __syncthreads();
    int start = bbase[k], end = bbase[k + 1];
    for (int e = start + tid; e < end; e += blockDim.x) {
        int2 r = recs[e];
        int dl = r.x >> 17;
        atomicAdd(&deg[dl], __int_as_float(r.y));
        atomicAdd(&cnt[dl], 1);
    }
    __syncthreads();
    for (int i = tid; i < nLoc; i += blockDim.x) {
        float d = rsqrtf(deg[i] + 1.0f);
        wdst[i] = d;
        dis[lo + i] = d;
        indeg[lo + i] = cnt[i];
    }
    if (tid < NB) sc[tid] = (tid < nLoc) ? cnt[tid] : 0;
    __syncthreads();
    // inclusive scan over 128 bins
    for (int off = 1; off < NB; off <<= 1) {
        int add = (tid < NB && tid >= off) ? sc[tid - off] : 0;
        __syncthreads();
        if (tid < NB) sc[tid] += add;
        __syncthreads();
    }
    if (tid < nLoc) {
        int ex = start + sc[tid] - cnt[tid];   // exclusive position
        offs[lo + tid] = ex;
        curs[tid] = ex;
    }
    __syncthreads();
    for (int e = start + tid; e < end; e += blockDim.x) {
        int2 r = recs[e];
        int src = r.x & 0x1FFFF;
        int dl = r.x >> 17;
        float pw = __int_as_float(r.y) * wdst[dl];   // ea * dis[dst]
        int pos = atomicAdd(&curs[dl], 1);
        csr[pos] = make_int2(src, __float_as_int(pw));
    }
}

// ---- tiled GEMM: 64 rows x 64 cols per block, X transposed in LDS ----
// Yb[n,HID] = bf16( dis[n] * (X[n,K] @ W[K,HID]) ).  4x4 register tile/thread.
template <int K>
__global__ __launch_bounds__(256) void gemm_kernel(const float* __restrict__ X,
                                                   const float* __restrict__ W,
                                                   const float* __restrict__ dis,
                                                   ushort_t* __restrict__ Yb) {
    __shared__ float w_lds[K * HID];     // [K][64]
    __shared__ float x_lds[K][65];       // transposed [k][row], pad 65
    int tid = threadIdx.x;
    int rowbase = blockIdx.x * 64;
    for (int i = tid; i < K * HID; i += 256) w_lds[i] = W[i];
    for (int i = tid; i < 16 * K; i += 256) {
        int row = i / (K / 4);
        int k4 = i % (K / 4);
        int r = rowbase + row;
        float4 v = (r < NN) ? ((const float4*)(X + (size_t)r * K))[k4]
                            : make_float4(0.f, 0.f, 0.f, 0.f);
        x_lds[k4 * 4 + 0][row] = v.x;
        x_lds[k4 * 4 + 1][row] = v.y;
        x_lds[k4 * 4 + 2][row] = v.z;
        x_lds[k4 * 4 + 3][row] = v.w;
    }
    __syncthreads();
    int c0 = (tid & 15) * 4;
    int r0 = (tid >> 4) * 4;
    float acc[4][4] = {};
#pragma unroll 4
    for (int k = 0; k < K; ++k) {
        float x0 = x_lds[k][r0 + 0];
        float x1 = x_lds[k][r0 + 1];
        float x2 = x_lds[k][r0 + 2];
        float x3 = x_lds[k][r0 + 3];
        float4 wv = *(const float4*)&w_lds[k * HID + c0];
        acc[0][0] += x0 * wv.x; acc[0][1] += x0 * wv.y; acc[0][2] += x0 * wv.z; acc[0][3] += x0 * wv.w;
        acc[1][0] += x1 * wv.x; acc[1][1] += x1 * wv.y; acc[1][2] += x1 * wv.z; acc[1][3] += x1 * wv.w;
        acc[2][0] += x2 * wv.x; acc[2][1] += x2 * wv.y; acc[2][2] += x2 * wv.z; acc[2][3] += x2 * wv.w;
        acc[3][0] += x3 * wv.x; acc[3][1] += x3 * wv.y; acc[3][2] += x3 * wv.z; acc[3][3] += x3 * wv.w;
    }
#pragma unroll
    for (int i = 0; i < 4; ++i) {
        int r = rowbase + r0 + i;
        if (r < NN) {
            float dr = dis[r];
            ushort4 o;
            o.x = f2bf(dr * acc[i][0]); o.y = f2bf(dr * acc[i][1]);
            o.z = f2bf(dr * acc[i][2]); o.w = f2bf(dr * acc[i][3]);
            *(ushort4*)&Yb[(size_t)r * HID + c0] = o;
        }
    }
}

// OUT[node] = act( sum_e pw*HWb[src] + dis[node]*HWb[node] + bias )
// HWb rows pre-scaled by dis[row]. 1 wave/node; quarter q owns edge j+q,
// lane loads ushort4 (4 cols). 2x unrolled -> 2 independent load chains.
template <bool RELU>
__global__ void gather_kernel(const int2* __restrict__ csr,
                              const int* __restrict__ offs,
                              const int* __restrict__ indeg,
                              const float* __restrict__ dis,
                              const ushort_t* __restrict__ HWb,
                              const float* __restrict__ bias,
                              float* __restrict__ OUT) {
    int node = blockIdx.x * 4 + (threadIdx.x >> 6);
    int lane = threadIdx.x & 63;
    if (node >= NN) return;
    int q  = lane >> 4;
    int cl = lane & 15;
    int start = offs[node];
    int n = indeg[node];
    float a0 = 0.f, a1 = 0.f, a2 = 0.f, a3 = 0.f;
    float b0 = 0.f, b1 = 0.f, b2 = 0.f, b3 = 0.f;
    int j = 0;
    for (; j + 8 <= n; j += 8) {
        int2 ra = csr[start + j + q];
        int2 rb = csr[start + j + 4 + q];
        float wa = __int_as_float(ra.y);
        float wb = __int_as_float(rb.y);
        ushort4 va = *(const ushort4*)(HWb + ((size_t)ra.x << 6) + (cl << 2));
        ushort4 vb = *(const ushort4*)(HWb + ((size_t)rb.x << 6) + (cl << 2));
        a0 += wa * bf2f(va.x); a1 += wa * bf2f(va.y);
        a2 += wa * bf2f(va.z); a3 += wa * bf2f(va.w);
        b0 += wb * bf2f(vb.x); b1 += wb * bf2f(vb.y);
        b2 += wb * bf2f(vb.z); b3 += wb * bf2f(vb.w);
    }
    for (; j < n; j += 4) {
        int m = n - j;                         // >= 1
        int2 r = csr[start + j + min(q, m - 1)];
        float w = (q < m) ? __int_as_float(r.y) : 0.f;
        ushort4 v = *(const ushort4*)(HWb + ((size_t)r.x << 6) + (cl << 2));
        a0 += w * bf2f(v.x); a1 += w * bf2f(v.y);
        a2 += w * bf2f(v.z); a3 += w * bf2f(v.w);
    }
    a0 += b0; a1 += b1; a2 += b2; a3 += b3;
    a0 += __shfl_xor(a0, 16, 64); a0 += __shfl_xor(a0, 32, 64);
    a1 += __shfl_xor(a1, 16, 64); a1 += __shfl_xor(a1, 32, 64);
    a2 += __shfl_xor(a2, 16, 64); a2 += __shfl_xor(a2, 32, 64);
    a3 += __shfl_xor(a3, 16, 64); a3 += __shfl_xor(a3, 32, 64);
    if (q == 0) {
        float d = dis[node];
        ushort4 sv = *(const ushort4*)(HWb + ((size_t)node << 6) + (cl << 2));
        float4 bv = *(const float4*)(bias + (cl << 2));
        float o0 = a0 + d * bf2f(sv.x) + bv.x;
        float o1 = a1 + d * bf2f(sv.y) + bv.y;
        float o2 = a2 + d * bf2f(sv.z) + bv.z;
        float o3 = a3 + d * bf2f(sv.w) + bv.w;
        if (RELU) {
            o0 = fmaxf(o0, 0.f); o1 = fmaxf(o1, 0.f);
            o2 = fmaxf(o2, 0.f); o3 = fmaxf(o3, 0.f);
        }
        *(float4*)&OUT[((size_t)node << 6) + (cl << 2)] = make_float4(o0, o1, o2, o3);
    }
}

// gstart[g] = lower_bound(batch, g)   (batch sorted); gstart[NG] = NN
__global__ void gbounds_kernel(const int* __restrict__ batch, int* __restrict__ gstart) {
    int g = blockIdx.x * blockDim.x + threadIdx.x;
    if (g > NG) return;
    int lo = 0, hi = NN;
    while (lo < hi) {
        int mid = (lo + hi) >> 1;
        if (batch[mid] < g) lo = mid + 1; else hi = mid;
    }
    gstart[g] = lo;
}

// out[g] = (mean of H rows in [gstart[g],gstart[g+1])) . Wlin + blin  (4 waves/graph)
__global__ void pool_head_kernel(const float* __restrict__ H,
                                 const int* __restrict__ gstart,
                                 const float* __restrict__ Wlin,
                                 const float* __restrict__ blin,
                                 float* __restrict__ out) {
    __shared__ float part[4];
    int g = blockIdx.x;
    int lane = threadIdx.x & 63;
    int wv = threadIdx.x >> 6;
    int s = gstart[g], e = gstart[g + 1];
    float wl = Wlin[lane];
    float a = 0.f;
    for (int i = s + wv; i < e; i += 4) a += H[(size_t)i * HID + lane];
    float v = a * wl;
    for (int off = 32; off > 0; off >>= 1) v += __shfl_down(v, off, 64);
    if (lane == 0) part[wv] = v;
    __syncthreads();
    if (threadIdx.x == 0) {
        float t = part[0] + part[1] + part[2] + part[3];
        out[g] = t / fmaxf((float)(e - s), 1.0f) + blin[0];
    }
}

extern "C" void kernel_launch(void* const* d_in, const int* in_sizes, int n_in,
                              void* d_out, int out_size, void* d_ws, size_t ws_size,
                              hipStream_t stream) {
    const float* x     = (const float*)d_in[0];
    const int*   ei    = (const int*)d_in[1];
    const float* ea    = (const float*)d_in[2];
    const int*   batch = (const int*)d_in[3];
    const float* W1    = (const float*)d_in[4];
    const float* b1    = (const float*)d_in[5];
    const float* W2    = (const float*)d_in[6];
    const float* b2    = (const float*)d_in[7];
    const float* Wlin  = (const float*)d_in[8];
    const float* blin  = (const float*)d_in[9];
    float*       out   = (float*)d_out;

    char* ws = (char*)d_ws;
    auto alloc = [&](size_t bytes) {
        void* p = (void*)ws;
        ws += (bytes + 255) / 256 * 256;
        return p;
    };
    float*    dis    = (float*)alloc((size_t)NN * 4);
    int*      indeg  = (int*)alloc((size_t)NN * 4);
    int*      offs   = (int*)alloc((size_t)NN * 4);
    int*      pcnt   = (int*)alloc((size_t)NBK * EBLK * 4);
    int*      tot    = (int*)alloc((size_t)NBK * 4);
    int*      bbase  = (int*)alloc((size_t)(NBK + 1) * 4);
    int*      gstart = (int*)alloc((size_t)(NG + 1) * 4);
    int2*     recs   = (int2*)alloc((size_t)NE * 8);   // bucket-grouped; dead after binfo2
    int2*     csr    = (int2*)alloc((size_t)NE * 8);   // node-grouped {src, ea*dis[dst]}
    float*    B      = (float*)alloc((size_t)NN * HID * 4);
    ushort_t* A      = (ushort_t*)recs;                // bf16 dis-scaled hw1/hw2

    // two-level bucket sort of edges by dst (no global atomics)
    cnt_kernel<<<EBLK, 256, 0, stream>>>(ei, pcnt);
    bscan_kernel<<<NBK, EBLK, 0, stream>>>(pcnt, tot);
    tscan_kernel<<<1, 512, 0, stream>>>(tot, bbase);
    scatter_kernel<<<EBLK, 256, 0, stream>>>(ei, ea, pcnt, bbase, recs);
    binfo2_kernel<<<NBK, 256, 0, stream>>>(recs, bbase, indeg, dis, offs, csr);

    // conv1: h1 = relu(gather(bf16(dis*(x@W1))) + self + b1)
    gemm_kernel<IN_DIM><<<(NN + 63) / 64, 256, 0, stream>>>(x, W1, dis, A);
    gather_kernel<true><<<(NN + 3) / 4, 256, 0, stream>>>(csr, offs, indeg, dis, A, b1, B);

    // conv2: h2 = gather(bf16(dis*(h1@W2))) + self + b2
    gemm_kernel<HID><<<(NN + 63) / 64, 256, 0, stream>>>(B, W2, dis, A);
    gather_kernel<false><<<(NN + 3) / 4, 256, 0, stream>>>(csr, offs, indeg, dis, A, b2, B);

    // mean-pool per sorted-contiguous graph range + head
    gbounds_kernel<<<(NG + 256) / 256, 256, 0, stream>>>(batch, gstart);
    pool_head_kernel<<<NG, 256, 0, stream>>>(B, gstart, Wlin, blin, out);
}

// Round 11
// 171.338 us; speedup vs baseline: 9.8398x; 1.0927x over previous
//
#include <hip/hip_runtime.h>

#define NN 50000
#define NE 1600000
#define NG 512
#define IN_DIM 128
#define HID 64

#define NB 128                       // nodes per bucket
#define NBK ((NN + NB - 1) / NB)     // 391 buckets
#define EBLK 512                     // edge-pass blocks
#define EPB (NE / EBLK)              // 3125 edges per block

typedef unsigned short ushort_t;
typedef unsigned int uint_t;

// float -> bf16 (RNE)
static __device__ __forceinline__ ushort_t f2bf(float f) {
    uint_t u = __float_as_uint(f);
    u += 0x7FFFu + ((u >> 16) & 1u);
    return (ushort_t)(u >> 16);
}
static __device__ __forceinline__ float bflo(uint_t u) { return __uint_as_float(u << 16); }
static __device__ __forceinline__ float bfhi(uint_t u) { return __uint_as_float(u & 0xFFFF0000u); }

// ---- pass 1: per-block coarse histogram of dst>>7 ----
__global__ void cnt_kernel(const int* __restrict__ ei, int* __restrict__ pcnt) {
    __shared__ int h[NBK];
    for (int i = threadIdx.x; i < NBK; i += blockDim.x) h[i] = 0;
    __syncthreads();
    int base = blockIdx.x * EPB;
    for (int e = base + threadIdx.x; e < base + EPB; e += blockDim.x)
        atomicAdd(&h[ei[NE + e] >> 7], 1);
    __syncthreads();
    for (int i = threadIdx.x; i < NBK; i += blockDim.x)
        pcnt[(size_t)i * EBLK + blockIdx.x] = h[i];
}

// ---- pass 2a: per-bucket exclusive scan over the EBLK partials ----
__global__ void bscan_kernel(int* __restrict__ pcnt, int* __restrict__ tot) {
    __shared__ int s[EBLK];
    int k = blockIdx.x, t = threadIdx.x;
    int v = pcnt[(size_t)k * EBLK + t];
    s[t] = v;
    __syncthreads();
    for (int off = 1; off < EBLK; off <<= 1) {
        int add = (t >= off) ? s[t - off] : 0;
        __syncthreads();
        s[t] += add;
        __syncthreads();
    }
    pcnt[(size_t)k * EBLK + t] = s[t] - v;   // exclusive within bucket
    if (t == EBLK - 1) tot[k] = s[t];
}

// ---- pass 2b: exclusive scan of bucket totals -> bbase[0..NBK] ----
__global__ void tscan_kernel(const int* __restrict__ tot, int* __restrict__ bbase) {
    __shared__ int s[512];
    int t = threadIdx.x;
    int v = (t < NBK) ? tot[t] : 0;
    s[t] = v;
    __syncthreads();
    for (int off = 1; off < 512; off <<= 1) {
        int add = (t >= off) ? s[t - off] : 0;
        __syncthreads();
        s[t] += add;
        __syncthreads();
    }
    if (t < NBK) bbase[t] = s[t] - v;
    if (t == NBK - 1) bbase[NBK] = s[t];
}

// ---- pass 3: scatter records {dl:7|src:17, ea} grouped by bucket ----
__global__ void scatter_kernel(const int* __restrict__ ei, const float* __restrict__ ea,
                               const int* __restrict__ pcnt, const int* __restrict__ bbase,
                               int2* __restrict__ recs) {
    __shared__ int curs[NBK];
    int b = blockIdx.x;
    for (int i = threadIdx.x; i < NBK; i += blockDim.x)
        curs[i] = bbase[i] + pcnt[(size_t)i * EBLK + b];
    __syncthreads();
    int base = b * EPB;
    for (int e = base + threadIdx.x; e < base + EPB; e += blockDim.x) {
        int dst = ei[NE + e];
        int src = ei[e];
        int k = dst >> 7;
        int pos = atomicAdd(&curs[k], 1);
        recs[pos] = make_int2(((dst & 127) << 17) | src, __float_as_int(ea[e]));
    }
}

// ---- merged bucket pass: deg/indeg + in-bucket scan -> offs, dis; then
//      scatter bucket recs to exact per-node CSR {src, ea*dis[dst]} ----
__global__ void binfo2_kernel(const int2* __restrict__ recs, const int* __restrict__ bbase,
                              int* __restrict__ indeg, float* __restrict__ dis,
                              int* __restrict__ offs, int2* __restrict__ csr) {
    __shared__ float deg[NB];
    __shared__ int cnt[NB];
    __shared__ int sc[NB];
    __shared__ int curs[NB];
    __shared__ float wdst[NB];
    int k = blockIdx.x;
    int lo = k * NB;
    int nLoc = min(NB, NN - lo);
    int tid = threadIdx.x;
    for (int i = tid; i < nLoc; i += blockDim.x) { deg[i] = 0.f; cnt[i] = 0; }
    __syncthreads();
    int start = bbase[k], end = bbase[k + 1];
    for (int e = start + tid; e < end; e += blockDim.x) {
        int2 r = recs[e];
        int dl = r.x >> 17;
        atomicAdd(&deg[dl], __int_as_float(r.y));
        atomicAdd(&cnt[dl], 1);
    }
    __syncthreads();
    for (int i = tid; i < nLoc; i += blockDim.x) {
        float d = rsqrtf(deg[i] + 1.0f);
        wdst[i] = d;
        dis[lo + i] = d;
        indeg[lo + i] = cnt[i];
    }
    if (tid < NB) sc[tid] = (tid < nLoc) ? cnt[tid] : 0;
    __syncthreads();
    // inclusive scan over 128 bins
    for (int off = 1; off < NB; off <<= 1) {
        int add = (tid < NB && tid >= off) ? sc[tid - off] : 0;
        __syncthreads();
        if (tid < NB) sc[tid] += add;
        __syncthreads();
    }
    if (tid < nLoc) {
        int ex = start + sc[tid] - cnt[tid];   // exclusive position
        offs[lo + tid] = ex;
        curs[tid] = ex;
    }
    __syncthreads();
    for (int e = start + tid; e < end; e += blockDim.x) {
        int2 r = recs[e];
        int src = r.x & 0x1FFFF;
        int dl = r.x >> 17;
        float pw = __int_as_float(r.y) * wdst[dl];   // ea * dis[dst]
        int pos = atomicAdd(&curs[dl], 1);
        csr[pos] = make_int2(src, __float_as_int(pw));
    }
}

// ---- tiled GEMM: 64 rows x 64 cols per block, X transposed in LDS ----
// Yb[n,HID] = bf16( dis[n] * (X[n,K] @ W[K,HID]) ).  4x4 register tile/thread.
template <int K>
__global__ __launch_bounds__(256) void gemm_kernel(const float* __restrict__ X,
                                                   const float* __restrict__ W,
                                                   const float* __restrict__ dis,
                                                   ushort_t* __restrict__ Yb) {
    __shared__ float w_lds[K * HID];     // [K][64]
    __shared__ float x_lds[K][65];       // transposed [k][row], pad 65
    int tid = threadIdx.x;
    int rowbase = blockIdx.x * 64;
    for (int i = tid; i < K * HID; i += 256) w_lds[i] = W[i];
    for (int i = tid; i < 16 * K; i += 256) {
        int row = i / (K / 4);
        int k4 = i % (K / 4);
        int r = rowbase + row;
        float4 v = (r < NN) ? ((const float4*)(X + (size_t)r * K))[k4]
                            : make_float4(0.f, 0.f, 0.f, 0.f);
        x_lds[k4 * 4 + 0][row] = v.x;
        x_lds[k4 * 4 + 1][row] = v.y;
        x_lds[k4 * 4 + 2][row] = v.z;
        x_lds[k4 * 4 + 3][row] = v.w;
    }
    __syncthreads();
    int c0 = (tid & 15) * 4;
    int r0 = (tid >> 4) * 4;
    float acc[4][4] = {};
#pragma unroll 4
    for (int k = 0; k < K; ++k) {
        float x0 = x_lds[k][r0 + 0];
        float x1 = x_lds[k][r0 + 1];
        float x2 = x_lds[k][r0 + 2];
        float x3 = x_lds[k][r0 + 3];
        float4 wv = *(const float4*)&w_lds[k * HID + c0];
        acc[0][0] += x0 * wv.x; acc[0][1] += x0 * wv.y; acc[0][2] += x0 * wv.z; acc[0][3] += x0 * wv.w;
        acc[1][0] += x1 * wv.x; acc[1][1] += x1 * wv.y; acc[1][2] += x1 * wv.z; acc[1][3] += x1 * wv.w;
        acc[2][0] += x2 * wv.x; acc[2][1] += x2 * wv.y; acc[2][2] += x2 * wv.z; acc[2][3] += x2 * wv.w;
        acc[3][0] += x3 * wv.x; acc[3][1] += x3 * wv.y; acc[3][2] += x3 * wv.z; acc[3][3] += x3 * wv.w;
    }
#pragma unroll
    for (int i = 0; i < 4; ++i) {
        int r = rowbase + r0 + i;
        if (r < NN) {
            float dr = dis[r];
            ushort4 o;
            o.x = f2bf(dr * acc[i][0]); o.y = f2bf(dr * acc[i][1]);
            o.z = f2bf(dr * acc[i][2]); o.w = f2bf(dr * acc[i][3]);
            *(ushort4*)&Yb[(size_t)r * HID + c0] = o;
        }
    }
}

// OUT[node] = act( sum_e pw*HWb[src] + dis[node]*HWb[node] + bias )
// HWb rows pre-scaled by dis[row]. 1 wave/node; oct o (8 lanes) owns edge j+o,
// lane loads uint4 = 8 bf16 cols (16B). 8 edges per VMEM instruction pair.
template <bool RELU>
__global__ void gather_kernel(const int2* __restrict__ csr,
                              const int* __restrict__ offs,
                              const int* __restrict__ indeg,
                              const float* __restrict__ dis,
                              const ushort_t* __restrict__ HWb,
                              const float* __restrict__ bias,
                              float* __restrict__ OUT) {
    int node = blockIdx.x * 4 + (threadIdx.x >> 6);
    int lane = threadIdx.x & 63;
    if (node >= NN) return;
    int o  = lane >> 3;        // oct 0..7: edge slot
    int cl = lane & 7;         // col group: cols cl*8 .. cl*8+7
    int start = offs[node];
    int n = indeg[node];
    float a0 = 0.f, a1 = 0.f, a2 = 0.f, a3 = 0.f;
    float a4 = 0.f, a5 = 0.f, a6 = 0.f, a7 = 0.f;
    int j = 0;
#pragma unroll 2
    for (; j + 8 <= n; j += 8) {
        int2 r = csr[start + j + o];
        float w = __int_as_float(r.y);
        uint4 v = *(const uint4*)(HWb + ((size_t)r.x << 6) + (cl << 3));
        a0 += w * bflo(v.x); a1 += w * bfhi(v.x);
        a2 += w * bflo(v.y); a3 += w * bfhi(v.y);
        a4 += w * bflo(v.z); a5 += w * bfhi(v.z);
        a6 += w * bflo(v.w); a7 += w * bfhi(v.w);
    }
    if (j < n) {
        int m = n - j;
        if (o < m) {                     // exec-masked: inactive octs fetch nothing
            int2 r = csr[start + j + o];
            float w = __int_as_float(r.y);
            uint4 v = *(const uint4*)(HWb + ((size_t)r.x << 6) + (cl << 3));
            a0 += w * bflo(v.x); a1 += w * bfhi(v.x);
            a2 += w * bflo(v.y); a3 += w * bfhi(v.y);
            a4 += w * bflo(v.z); a5 += w * bfhi(v.z);
            a6 += w * bflo(v.w); a7 += w * bfhi(v.w);
        }
    }
    // reduce across the 8 octs
    a0 += __shfl_xor(a0, 8, 64); a0 += __shfl_xor(a0, 16, 64); a0 += __shfl_xor(a0, 32, 64);
    a1 += __shfl_xor(a1, 8, 64); a1 += __shfl_xor(a1, 16, 64); a1 += __shfl_xor(a1, 32, 64);
    a2 += __shfl_xor(a2, 8, 64); a2 += __shfl_xor(a2, 16, 64); a2 += __shfl_xor(a2, 32, 64);
    a3 += __shfl_xor(a3, 8, 64); a3 += __shfl_xor(a3, 16, 64); a3 += __shfl_xor(a3, 32, 64);
    a4 += __shfl_xor(a4, 8, 64); a4 += __shfl_xor(a4, 16, 64); a4 += __shfl_xor(a4, 32, 64);
    a5 += __shfl_xor(a5, 8, 64); a5 += __shfl_xor(a5, 16, 64); a5 += __shfl_xor(a5, 32, 64);
    a6 += __shfl_xor(a6, 8, 64); a6 += __shfl_xor(a6, 16, 64); a6 += __shfl_xor(a6, 32, 64);
    a7 += __shfl_xor(a7, 8, 64); a7 += __shfl_xor(a7, 16, 64); a7 += __shfl_xor(a7, 32, 64);
    if (o == 0) {
        float d = dis[node];
        uint4 sv = *(const uint4*)(HWb + ((size_t)node << 6) + (cl << 3));
        const float4* bv = (const float4*)(bias + (cl << 3));
        float4 b0 = bv[0], b1 = bv[1];
        float o0 = a0 + d * bflo(sv.x) + b0.x;
        float o1 = a1 + d * bfhi(sv.x) + b0.y;
        float o2 = a2 + d * bflo(sv.y) + b0.z;
        float o3 = a3 + d * bfhi(sv.y) + b0.w;
        float o4 = a4 + d * bflo(sv.z) + b1.x;
        float o5 = a5 + d * bfhi(sv.z) + b1.y;
        float o6 = a6 + d * bflo(sv.w) + b1.z;
        float o7 = a7 + d * bfhi(sv.w) + b1.w;
        if (RELU) {
            o0 = fmaxf(o0, 0.f); o1 = fmaxf(o1, 0.f);
            o2 = fmaxf(o2, 0.f); o3 = fmaxf(o3, 0.f);
            o4 = fmaxf(o4, 0.f); o5 = fmaxf(o5, 0.f);
            o6 = fmaxf(o6, 0.f); o7 = fmaxf(o7, 0.f);
        }
        float* op = &OUT[((size_t)node << 6) + (cl << 3)];
        *(float4*)op       = make_float4(o0, o1, o2, o3);
        *(float4*)(op + 4) = make_float4(o4, o5, o6, o7);
    }
}

// out[g] = (mean of H rows in batch range g) . Wlin + blin  (4 waves/graph)
// graph bounds found by in-block binary search (batch sorted).
__global__ void pool_head_kernel(const float* __restrict__ H,
                                 const int* __restrict__ batch,
                                 const float* __restrict__ Wlin,
                                 const float* __restrict__ blin,
                                 float* __restrict__ out) {
    __shared__ float part[4];
    __shared__ int bnd[2];
    int g = blockIdx.x;
    if (threadIdx.x < 2) {
        int target = g + threadIdx.x;
        int lo = 0, hi = NN;
        while (lo < hi) {
            int mid = (lo + hi) >> 1;
            if (batch[mid] < target) lo = mid + 1; else hi = mid;
        }
        bnd[threadIdx.x] = lo;
    }
    __syncthreads();
    int s = bnd[0], e = bnd[1];
    int lane = threadIdx.x & 63;
    int wv = threadIdx.x >> 6;
    float wl = Wlin[lane];
    float a = 0.f;
    for (int i = s + wv; i < e; i += 4) a += H[(size_t)i * HID + lane];
    float v = a * wl;
    for (int off = 32; off > 0; off >>= 1) v += __shfl_down(v, off, 64);
    if (lane == 0) part[wv] = v;
    __syncthreads();
    if (threadIdx.x == 0) {
        float t = part[0] + part[1] + part[2] + part[3];
        out[g] = t / fmaxf((float)(e - s), 1.0f) + blin[0];
    }
}

extern "C" void kernel_launch(void* const* d_in, const int* in_sizes, int n_in,
                              void* d_out, int out_size, void* d_ws, size_t ws_size,
                              hipStream_t stream) {
    const float* x     = (const float*)d_in[0];
    const int*   ei    = (const int*)d_in[1];
    const float* ea    = (const float*)d_in[2];
    const int*   batch = (const int*)d_in[3];
    const float* W1    = (const float*)d_in[4];
    const float* b1    = (const float*)d_in[5];
    const float* W2    = (const float*)d_in[6];
    const float* b2    = (const float*)d_in[7];
    const float* Wlin  = (const float*)d_in[8];
    const float* blin  = (const float*)d_in[9];
    float*       out   = (float*)d_out;

    char* ws = (char*)d_ws;
    auto alloc = [&](size_t bytes) {
        void* p = (void*)ws;
        ws += (bytes + 255) / 256 * 256;
        return p;
    };
    float*    dis    = (float*)alloc((size_t)NN * 4);
    int*      indeg  = (int*)alloc((size_t)NN * 4);
    int*      offs   = (int*)alloc((size_t)NN * 4);
    int*      pcnt   = (int*)alloc((size_t)NBK * EBLK * 4);
    int*      tot    = (int*)alloc((size_t)NBK * 4);
    int*      bbase  = (int*)alloc((size_t)(NBK + 1) * 4);
    int2*     recs   = (int2*)alloc((size_t)NE * 8);   // bucket-grouped; dead after binfo2
    int2*     csr    = (int2*)alloc((size_t)NE * 8);   // node-grouped {src, ea*dis[dst]}
    float*    B      = (float*)alloc((size_t)NN * HID * 4);
    ushort_t* A      = (ushort_t*)recs;                // bf16 dis-scaled hw1/hw2

    // two-level bucket sort of edges by dst (no global atomics)
    cnt_kernel<<<EBLK, 256, 0, stream>>>(ei, pcnt);
    bscan_kernel<<<NBK, EBLK, 0, stream>>>(pcnt, tot);
    tscan_kernel<<<1, 512, 0, stream>>>(tot, bbase);
    scatter_kernel<<<EBLK, 256, 0, stream>>>(ei, ea, pcnt, bbase, recs);
    binfo2_kernel<<<NBK, 256, 0, stream>>>(recs, bbase, indeg, dis, offs, csr);

    // conv1: h1 = relu(gather(bf16(dis*(x@W1))) + self + b1)
    gemm_kernel<IN_DIM><<<(NN + 63) / 64, 256, 0, stream>>>(x, W1, dis, A);
    gather_kernel<true><<<(NN + 3) / 4, 256, 0, stream>>>(csr, offs, indeg, dis, A, b1, B);

    // conv2: h2 = gather(bf16(dis*(h1@W2))) + self + b2
    gemm_kernel<HID><<<(NN + 63) / 64, 256, 0, stream>>>(B, W2, dis, A);
    gather_kernel<false><<<(NN + 3) / 4, 256, 0, stream>>>(csr, offs, indeg, dis, A, b2, B);

    // mean-pool per sorted-contiguous graph range + head (bounds inline)
    pool_head_kernel<<<NG, 256, 0, stream>>>(B, batch, Wlin, blin, out);
}